// Round 1
// baseline (1376.184 us; speedup 1.0000x reference)
//
#include <hip/hip_runtime.h>

#define N_NODES 100000
#define N_EDGES 1600000
#define DIM 128
#define N_GRAPHS 1024

// ---------------- CSR build ----------------

__global__ void hist_kernel(const int* __restrict__ dst, int* __restrict__ deg) {
    int i = blockIdx.x * blockDim.x + threadIdx.x;
    int stride = gridDim.x * blockDim.x;
    for (; i < N_EDGES; i += stride) atomicAdd(&deg[dst[i]], 1);
}

__global__ __launch_bounds__(1024) void scan_kernel(int* __restrict__ off, int* __restrict__ cursor) {
    // off[0..N-1] holds degrees on entry; exit: off[0..N] = exclusive scan, cursor[i] = off[i]
    __shared__ int part[1024];
    int t = threadIdx.x;
    const int CH = (N_NODES + 1023) / 1024;
    int i0 = t * CH;
    int i1 = min(i0 + CH, N_NODES);
    int s = 0;
    for (int i = i0; i < i1; ++i) s += off[i];
    part[t] = s;
    __syncthreads();
    for (int o = 1; o < 1024; o <<= 1) {
        int v = (t >= o) ? part[t - o] : 0;
        __syncthreads();
        part[t] += v;
        __syncthreads();
    }
    int run = (t == 0) ? 0 : part[t - 1];
    for (int i = i0; i < i1; ++i) {
        int c = off[i];
        off[i] = run;
        cursor[i] = run;
        run += c;
    }
    if (t == 1023) off[N_NODES] = run;
}

__global__ void fill_kernel(const int* __restrict__ src, const int* __restrict__ dst,
                            int* __restrict__ cursor, int* __restrict__ csr) {
    int i = blockIdx.x * blockDim.x + threadIdx.x;
    int stride = gridDim.x * blockDim.x;
    for (; i < N_EDGES; i += stride) {
        int p = atomicAdd(&cursor[dst[i]], 1);
        csr[p] = src[i];
    }
}

// ---------------- W transpose (wt[l][k][d] = Wl[d][k]) ----------------

__global__ void transpose_w_kernel(const float* __restrict__ W1, const float* __restrict__ W2,
                                   const float* __restrict__ W3, float* __restrict__ wt) {
    int i = blockIdx.x * blockDim.x + threadIdx.x;
    if (i >= 3 * DIM * DIM) return;
    int l = i / (DIM * DIM);
    int r = i % (DIM * DIM);
    int d = r >> 7, k = r & 127;
    const float* W = (l == 0) ? W1 : (l == 1) ? W2 : W3;
    wt[l * DIM * DIM + k * DIM + d] = W[d * DIM + k];
}

// ---------------- aggregation: t[n] = (1+eps)*h[n] + sum_{s in N(n)} h[s] ----------------

__global__ __launch_bounds__(256) void agg_kernel(const float* __restrict__ hin, float* __restrict__ t,
                                                  const int* __restrict__ off, const int* __restrict__ csr,
                                                  const float* __restrict__ eps_arr, int layer) {
    int gtid = blockIdx.x * blockDim.x + threadIdx.x;
    int wave = gtid >> 6;
    int lane = threadIdx.x & 63;
    int nw = (gridDim.x * blockDim.x) >> 6;
    float se = 1.0f + eps_arr[layer];
    for (int n = wave; n < N_NODES; n += nw) {
        float2 v = ((const float2*)(hin + (size_t)n * DIM))[lane];
        float ax = v.x * se, ay = v.y * se;
        int k = off[n], e = off[n + 1];
        for (; k + 1 < e; k += 2) {
            int s0 = csr[k], s1 = csr[k + 1];
            float2 a = ((const float2*)(hin + (size_t)s0 * DIM))[lane];
            float2 b = ((const float2*)(hin + (size_t)s1 * DIM))[lane];
            ax += a.x + b.x;
            ay += a.y + b.y;
        }
        if (k < e) {
            int s0 = csr[k];
            float2 a = ((const float2*)(hin + (size_t)s0 * DIM))[lane];
            ax += a.x;
            ay += a.y;
        }
        float2 o;
        o.x = ax; o.y = ay;
        ((float2*)(t + (size_t)n * DIM))[lane] = o;
    }
}

// ---------------- GEMM: y = t @ W^T + b, fused per-column sum/sumsq ----------------
// block = 256 threads, 32 nodes/block (100000 = 3125 * 32 exactly)
// thread: g = tid>>5 owns nodes row0+g*4 .. +3, d0 = (tid&31)*4 owns 4 output dims

__global__ __launch_bounds__(256) void gemm_kernel(const float* __restrict__ t, const float* __restrict__ wt,
                                                   const float* __restrict__ bias, float* __restrict__ y,
                                                   float* __restrict__ colsum, float* __restrict__ colsumsq) {
    __shared__ float sred[2 * 8 * DIM];
    int tid = threadIdx.x;
    int d0 = (tid & 31) * 4;
    int g = tid >> 5;
    int row0 = blockIdx.x * 32 + g * 4;
    float acc[4][4] = {{0.0f}};
    for (int k = 0; k < DIM; k += 4) {
        float4 w0 = *(const float4*)(wt + (k + 0) * DIM + d0);
        float4 w1 = *(const float4*)(wt + (k + 1) * DIM + d0);
        float4 w2 = *(const float4*)(wt + (k + 2) * DIM + d0);
        float4 w3 = *(const float4*)(wt + (k + 3) * DIM + d0);
#pragma unroll
        for (int i = 0; i < 4; ++i) {
            float4 tv = *(const float4*)(t + (size_t)(row0 + i) * DIM + k);
            acc[i][0] += tv.x * w0.x + tv.y * w1.x + tv.z * w2.x + tv.w * w3.x;
            acc[i][1] += tv.x * w0.y + tv.y * w1.y + tv.z * w2.y + tv.w * w3.y;
            acc[i][2] += tv.x * w0.z + tv.y * w1.z + tv.z * w2.z + tv.w * w3.z;
            acc[i][3] += tv.x * w0.w + tv.y * w1.w + tv.z * w2.w + tv.w * w3.w;
        }
    }
    float4 bv = *(const float4*)(bias + d0);
    float ps[4] = {0, 0, 0, 0}, pq[4] = {0, 0, 0, 0};
#pragma unroll
    for (int i = 0; i < 4; ++i) {
        acc[i][0] += bv.x; acc[i][1] += bv.y; acc[i][2] += bv.z; acc[i][3] += bv.w;
        float4 o;
        o.x = acc[i][0]; o.y = acc[i][1]; o.z = acc[i][2]; o.w = acc[i][3];
        *(float4*)(y + (size_t)(row0 + i) * DIM + d0) = o;
#pragma unroll
        for (int j = 0; j < 4; ++j) {
            ps[j] += acc[i][j];
            pq[j] += acc[i][j] * acc[i][j];
        }
    }
#pragma unroll
    for (int j = 0; j < 4; ++j) {
        sred[g * DIM + d0 + j] = ps[j];
        sred[8 * DIM + g * DIM + d0 + j] = pq[j];
    }
    __syncthreads();
    if (tid < DIM) {
        float s = 0.0f, q = 0.0f;
#pragma unroll
        for (int g2 = 0; g2 < 8; ++g2) {
            s += sred[g2 * DIM + tid];
            q += sred[8 * DIM + g2 * DIM + tid];
        }
        atomicAdd(&colsum[tid], s);
        atomicAdd(&colsumsq[tid], q);
    }
}

// ---------------- BN finalize ----------------

__global__ void bnfin_kernel(float* __restrict__ colsum, float* __restrict__ colsumsq,
                             const float* __restrict__ gamma, const float* __restrict__ beta,
                             float* __restrict__ scale, float* __restrict__ shift) {
    int d = threadIdx.x;
    float m = colsum[d] * (1.0f / N_NODES);
    float v = colsumsq[d] * (1.0f / N_NODES) - m * m;
    float sc = gamma[d] * rsqrtf(v + 1e-5f);
    scale[d] = sc;
    shift[d] = beta[d] - m * sc;
    colsum[d] = 0.0f;
    colsumsq[d] = 0.0f;
}

// ---------------- BN apply + ReLU ----------------

__global__ __launch_bounds__(256) void apply_kernel(const float* __restrict__ y,
                                                    const float* __restrict__ scale,
                                                    const float* __restrict__ shift,
                                                    float* __restrict__ h) {
    int i = blockIdx.x * blockDim.x + threadIdx.x;
    int stride = gridDim.x * blockDim.x;
    const int TOT = N_NODES * DIM / 4;
    for (; i < TOT; i += stride) {
        int d0 = (i * 4) & 127;
        float4 v = ((const float4*)y)[i];
        float4 sc = *(const float4*)(scale + d0);
        float4 sh = *(const float4*)(shift + d0);
        float4 o;
        o.x = fmaxf(v.x * sc.x + sh.x, 0.0f);
        o.y = fmaxf(v.y * sc.y + sh.y, 0.0f);
        o.z = fmaxf(v.z * sc.z + sh.z, 0.0f);
        o.w = fmaxf(v.w * sc.w + sh.w, 0.0f);
        ((float4*)h)[i] = o;
    }
}

// ---------------- global mean pool (batch sorted) ----------------

__global__ __launch_bounds__(128) void pool_kernel(const float* __restrict__ h,
                                                   const int* __restrict__ batch,
                                                   float* __restrict__ out) {
    int gph = blockIdx.x;
    int d = threadIdx.x;
    int lo = 0, hi = N_NODES;
    while (lo < hi) {
        int mid = (lo + hi) >> 1;
        if (batch[mid] < gph) lo = mid + 1; else hi = mid;
    }
    int start = lo;
    hi = N_NODES;
    while (lo < hi) {
        int mid = (lo + hi) >> 1;
        if (batch[mid] < gph + 1) lo = mid + 1; else hi = mid;
    }
    int end = lo;
    float s = 0.0f;
    for (int n = start; n < end; ++n) s += h[(size_t)n * DIM + d];
    out[gph * DIM + d] = s / fmaxf((float)(end - start), 1.0f);
}

// ---------------- launch ----------------

extern "C" void kernel_launch(void* const* d_in, const int* in_sizes, int n_in,
                              void* d_out, int out_size, void* d_ws, size_t ws_size,
                              hipStream_t stream) {
    const float* x = (const float*)d_in[0];
    const int* ei = (const int*)d_in[1];
    const int* batch = (const int*)d_in[2];
    const float* Wp[3] = {(const float*)d_in[3], (const float*)d_in[5], (const float*)d_in[7]};
    const float* bp[3] = {(const float*)d_in[4], (const float*)d_in[6], (const float*)d_in[8]};
    const float* eps = (const float*)d_in[9];
    const float* gamma = (const float*)d_in[10];
    const float* beta = (const float*)d_in[11];
    float* out = (float*)d_out;

    char* ws = (char*)d_ws;
    size_t o = 0;
    auto alloc = [&](size_t bytes) {
        void* p = ws + o;
        o = (o + bytes + 255) & ~(size_t)255;
        return p;
    };
    int* off = (int*)alloc((N_NODES + 1) * sizeof(int));
    int* cursor = (int*)alloc(N_NODES * sizeof(int));
    int* csr = (int*)alloc(N_EDGES * sizeof(int));
    float* wt = (float*)alloc(3 * DIM * DIM * sizeof(float));
    float* colsum = (float*)alloc(DIM * sizeof(float));
    float* colsumsq = (float*)alloc(DIM * sizeof(float));
    float* bnsc = (float*)alloc(DIM * sizeof(float));
    float* bnsh = (float*)alloc(DIM * sizeof(float));
    float* bufA = (float*)alloc((size_t)N_NODES * DIM * sizeof(float));
    float* bufB = (float*)alloc((size_t)N_NODES * DIM * sizeof(float));

    hipMemsetAsync(off, 0, (N_NODES + 1) * sizeof(int), stream);
    hipMemsetAsync(colsum, 0, DIM * sizeof(float), stream);
    hipMemsetAsync(colsumsq, 0, DIM * sizeof(float), stream);

    hist_kernel<<<1024, 256, 0, stream>>>(ei + N_EDGES, off);
    scan_kernel<<<1, 1024, 0, stream>>>(off, cursor);
    fill_kernel<<<1024, 256, 0, stream>>>(ei, ei + N_EDGES, cursor, csr);
    transpose_w_kernel<<<(3 * DIM * DIM + 255) / 256, 256, 0, stream>>>(Wp[0], Wp[1], Wp[2], wt);

    const float* hin = x;
    float* tbuf = bufA;
    float* ybuf = bufB;
    for (int l = 0; l < 3; ++l) {
        agg_kernel<<<2048, 256, 0, stream>>>(hin, tbuf, off, csr, eps, l);
        gemm_kernel<<<N_NODES / 32, 256, 0, stream>>>(tbuf, wt + l * DIM * DIM, bp[l], ybuf,
                                                      colsum, colsumsq);
        bnfin_kernel<<<1, DIM, 0, stream>>>(colsum, colsumsq, gamma + l * DIM, beta + l * DIM,
                                            bnsc, bnsh);
        apply_kernel<<<4096, 256, 0, stream>>>(ybuf, bnsc, bnsh, tbuf);
        hin = tbuf;
        float* tmp = tbuf; tbuf = ybuf; ybuf = tmp;
    }
    pool_kernel<<<N_GRAPHS, DIM, 0, stream>>>(hin, batch, out);
}

// Round 2
// 1148.560 us; speedup vs baseline: 1.1982x; 1.1982x over previous
//
#include <hip/hip_runtime.h>

#define N_NODES 100000
#define N_EDGES 1600000
#define DIM 128
#define N_GRAPHS 1024

#define SCAN_BLOCK 256
#define SCAN_NB ((N_NODES + SCAN_BLOCK - 1) / SCAN_BLOCK)  // 391

// ---------------- CSR build ----------------

__global__ void hist_kernel(const int* __restrict__ dst, int* __restrict__ deg) {
    int i = blockIdx.x * blockDim.x + threadIdx.x;
    int stride = gridDim.x * blockDim.x;
    for (; i < N_EDGES; i += stride) atomicAdd(&deg[dst[i]], 1);
}

// pass 1: per-block sums of deg
__global__ __launch_bounds__(SCAN_BLOCK) void scan_partial_kernel(const int* __restrict__ deg,
                                                                  int* __restrict__ partials) {
    __shared__ int red[SCAN_BLOCK / 64];
    int i = blockIdx.x * SCAN_BLOCK + threadIdx.x;
    int v = (i < N_NODES) ? deg[i] : 0;
    // wave reduce
    for (int o = 32; o > 0; o >>= 1) v += __shfl_down(v, o, 64);
    if ((threadIdx.x & 63) == 0) red[threadIdx.x >> 6] = v;
    __syncthreads();
    if (threadIdx.x == 0) {
        int s = 0;
#pragma unroll
        for (int w = 0; w < SCAN_BLOCK / 64; ++w) s += red[w];
        partials[blockIdx.x] = s;
    }
}

// pass 2: exclusive-scan the 391 partials in one small block; write off[N_NODES]=total
__global__ __launch_bounds__(512) void scan_partials_kernel(int* __restrict__ partials,
                                                            int* __restrict__ off) {
    __shared__ int sm[512];
    int t = threadIdx.x;
    int v = (t < SCAN_NB) ? partials[t] : 0;
    sm[t] = v;
    __syncthreads();
    for (int o = 1; o < 512; o <<= 1) {
        int u = (t >= o) ? sm[t - o] : 0;
        __syncthreads();
        sm[t] += u;
        __syncthreads();
    }
    if (t < SCAN_NB) partials[t] = sm[t] - v;  // exclusive
    if (t == 0) off[N_NODES] = sm[511];        // total (tail entries are 0)
}

// pass 3: block-local exclusive scan + block offset -> off, cursor
__global__ __launch_bounds__(SCAN_BLOCK) void scan_scatter_kernel(const int* __restrict__ deg,
                                                                  const int* __restrict__ partials,
                                                                  int* __restrict__ off,
                                                                  int* __restrict__ cursor) {
    __shared__ int sm[SCAN_BLOCK];
    int t = threadIdx.x;
    int i = blockIdx.x * SCAN_BLOCK + t;
    int v = (i < N_NODES) ? deg[i] : 0;
    sm[t] = v;
    __syncthreads();
    for (int o = 1; o < SCAN_BLOCK; o <<= 1) {
        int u = (t >= o) ? sm[t - o] : 0;
        __syncthreads();
        sm[t] += u;
        __syncthreads();
    }
    if (i < N_NODES) {
        int r = partials[blockIdx.x] + sm[t] - v;
        off[i] = r;
        cursor[i] = r;
    }
}

__global__ void fill_kernel(const int* __restrict__ src, const int* __restrict__ dst,
                            int* __restrict__ cursor, int* __restrict__ csr) {
    int i = blockIdx.x * blockDim.x + threadIdx.x;
    int stride = gridDim.x * blockDim.x;
    for (; i < N_EDGES; i += stride) {
        int p = atomicAdd(&cursor[dst[i]], 1);
        csr[p] = src[i];
    }
}

// ---------------- W transpose (wt[l][k][d] = Wl[d][k]) ----------------

__global__ void transpose_w_kernel(const float* __restrict__ W1, const float* __restrict__ W2,
                                   const float* __restrict__ W3, float* __restrict__ wt) {
    int i = blockIdx.x * blockDim.x + threadIdx.x;
    if (i >= 3 * DIM * DIM) return;
    int l = i / (DIM * DIM);
    int r = i % (DIM * DIM);
    int d = r >> 7, k = r & 127;
    const float* W = (l == 0) ? W1 : (l == 1) ? W2 : W3;
    wt[l * DIM * DIM + k * DIM + d] = W[d * DIM + k];
}

// ---------------- aggregation: t[n] = (1+eps)*h[n] + sum_{s in N(n)} h[s] ----------------
// 32 lanes per node, float4 per lane (32*16B = 512B = one row)

__global__ __launch_bounds__(256) void agg_kernel(const float* __restrict__ hin, float* __restrict__ t,
                                                  const int* __restrict__ off, const int* __restrict__ csr,
                                                  const float* __restrict__ eps_arr, int layer) {
    int gtid = blockIdx.x * blockDim.x + threadIdx.x;
    int grp = gtid >> 5;
    int lane = threadIdx.x & 31;
    int ngrp = (gridDim.x * blockDim.x) >> 5;
    float se = 1.0f + eps_arr[layer];
    for (int n = grp; n < N_NODES; n += ngrp) {
        float4 v = ((const float4*)(hin + (size_t)n * DIM))[lane];
        float ax = v.x * se, ay = v.y * se, az = v.z * se, aw = v.w * se;
        int k = off[n], e = off[n + 1];
        for (; k + 3 < e; k += 4) {
            int s0 = csr[k], s1 = csr[k + 1], s2 = csr[k + 2], s3 = csr[k + 3];
            float4 a = ((const float4*)(hin + (size_t)s0 * DIM))[lane];
            float4 b = ((const float4*)(hin + (size_t)s1 * DIM))[lane];
            float4 c = ((const float4*)(hin + (size_t)s2 * DIM))[lane];
            float4 d = ((const float4*)(hin + (size_t)s3 * DIM))[lane];
            ax += (a.x + b.x) + (c.x + d.x);
            ay += (a.y + b.y) + (c.y + d.y);
            az += (a.z + b.z) + (c.z + d.z);
            aw += (a.w + b.w) + (c.w + d.w);
        }
        for (; k < e; ++k) {
            int s0 = csr[k];
            float4 a = ((const float4*)(hin + (size_t)s0 * DIM))[lane];
            ax += a.x; ay += a.y; az += a.z; aw += a.w;
        }
        float4 o;
        o.x = ax; o.y = ay; o.z = az; o.w = aw;
        ((float4*)(t + (size_t)n * DIM))[lane] = o;
    }
}

// ---------------- GEMM: y = t @ W^T + b, fused per-column sum/sumsq ----------------

__global__ __launch_bounds__(256) void gemm_kernel(const float* __restrict__ t, const float* __restrict__ wt,
                                                   const float* __restrict__ bias, float* __restrict__ y,
                                                   float* __restrict__ colsum, float* __restrict__ colsumsq) {
    __shared__ float sred[2 * 8 * DIM];
    int tid = threadIdx.x;
    int d0 = (tid & 31) * 4;
    int g = tid >> 5;
    int row0 = blockIdx.x * 32 + g * 4;
    float acc[4][4] = {{0.0f}};
    for (int k = 0; k < DIM; k += 4) {
        float4 w0 = *(const float4*)(wt + (k + 0) * DIM + d0);
        float4 w1 = *(const float4*)(wt + (k + 1) * DIM + d0);
        float4 w2 = *(const float4*)(wt + (k + 2) * DIM + d0);
        float4 w3 = *(const float4*)(wt + (k + 3) * DIM + d0);
#pragma unroll
        for (int i = 0; i < 4; ++i) {
            float4 tv = *(const float4*)(t + (size_t)(row0 + i) * DIM + k);
            acc[i][0] += tv.x * w0.x + tv.y * w1.x + tv.z * w2.x + tv.w * w3.x;
            acc[i][1] += tv.x * w0.y + tv.y * w1.y + tv.z * w2.y + tv.w * w3.y;
            acc[i][2] += tv.x * w0.z + tv.y * w1.z + tv.z * w2.z + tv.w * w3.z;
            acc[i][3] += tv.x * w0.w + tv.y * w1.w + tv.z * w2.w + tv.w * w3.w;
        }
    }
    float4 bv = *(const float4*)(bias + d0);
    float ps[4] = {0, 0, 0, 0}, pq[4] = {0, 0, 0, 0};
#pragma unroll
    for (int i = 0; i < 4; ++i) {
        acc[i][0] += bv.x; acc[i][1] += bv.y; acc[i][2] += bv.z; acc[i][3] += bv.w;
        float4 o;
        o.x = acc[i][0]; o.y = acc[i][1]; o.z = acc[i][2]; o.w = acc[i][3];
        *(float4*)(y + (size_t)(row0 + i) * DIM + d0) = o;
#pragma unroll
        for (int j = 0; j < 4; ++j) {
            ps[j] += acc[i][j];
            pq[j] += acc[i][j] * acc[i][j];
        }
    }
#pragma unroll
    for (int j = 0; j < 4; ++j) {
        sred[g * DIM + d0 + j] = ps[j];
        sred[8 * DIM + g * DIM + d0 + j] = pq[j];
    }
    __syncthreads();
    if (tid < DIM) {
        float s = 0.0f, q = 0.0f;
#pragma unroll
        for (int g2 = 0; g2 < 8; ++g2) {
            s += sred[g2 * DIM + tid];
            q += sred[8 * DIM + g2 * DIM + tid];
        }
        atomicAdd(&colsum[tid], s);
        atomicAdd(&colsumsq[tid], q);
    }
}

// ---------------- BN finalize ----------------

__global__ void bnfin_kernel(float* __restrict__ colsum, float* __restrict__ colsumsq,
                             const float* __restrict__ gamma, const float* __restrict__ beta,
                             float* __restrict__ scale, float* __restrict__ shift) {
    int d = threadIdx.x;
    float m = colsum[d] * (1.0f / N_NODES);
    float v = colsumsq[d] * (1.0f / N_NODES) - m * m;
    float sc = gamma[d] * rsqrtf(v + 1e-5f);
    scale[d] = sc;
    shift[d] = beta[d] - m * sc;
    colsum[d] = 0.0f;
    colsumsq[d] = 0.0f;
}

// ---------------- BN apply + ReLU ----------------

__global__ __launch_bounds__(256) void apply_kernel(const float* __restrict__ y,
                                                    const float* __restrict__ scale,
                                                    const float* __restrict__ shift,
                                                    float* __restrict__ h) {
    int i = blockIdx.x * blockDim.x + threadIdx.x;
    int stride = gridDim.x * blockDim.x;
    const int TOT = N_NODES * DIM / 4;
    for (; i < TOT; i += stride) {
        int d0 = (i * 4) & 127;
        float4 v = ((const float4*)y)[i];
        float4 sc = *(const float4*)(scale + d0);
        float4 sh = *(const float4*)(shift + d0);
        float4 o;
        o.x = fmaxf(v.x * sc.x + sh.x, 0.0f);
        o.y = fmaxf(v.y * sc.y + sh.y, 0.0f);
        o.z = fmaxf(v.z * sc.z + sh.z, 0.0f);
        o.w = fmaxf(v.w * sc.w + sh.w, 0.0f);
        ((float4*)h)[i] = o;
    }
}

// ---------------- global mean pool (batch sorted) ----------------

__global__ __launch_bounds__(128) void pool_kernel(const float* __restrict__ h,
                                                   const int* __restrict__ batch,
                                                   float* __restrict__ out) {
    int gph = blockIdx.x;
    int d = threadIdx.x;
    int lo = 0, hi = N_NODES;
    while (lo < hi) {
        int mid = (lo + hi) >> 1;
        if (batch[mid] < gph) lo = mid + 1; else hi = mid;
    }
    int start = lo;
    hi = N_NODES;
    while (lo < hi) {
        int mid = (lo + hi) >> 1;
        if (batch[mid] < gph + 1) lo = mid + 1; else hi = mid;
    }
    int end = lo;
    float s = 0.0f;
    for (int n = start; n < end; ++n) s += h[(size_t)n * DIM + d];
    out[gph * DIM + d] = s / fmaxf((float)(end - start), 1.0f);
}

// ---------------- launch ----------------

extern "C" void kernel_launch(void* const* d_in, const int* in_sizes, int n_in,
                              void* d_out, int out_size, void* d_ws, size_t ws_size,
                              hipStream_t stream) {
    const float* x = (const float*)d_in[0];
    const int* ei = (const int*)d_in[1];
    const int* batch = (const int*)d_in[2];
    const float* Wp[3] = {(const float*)d_in[3], (const float*)d_in[5], (const float*)d_in[7]};
    const float* bp[3] = {(const float*)d_in[4], (const float*)d_in[6], (const float*)d_in[8]};
    const float* eps = (const float*)d_in[9];
    const float* gamma = (const float*)d_in[10];
    const float* beta = (const float*)d_in[11];
    float* out = (float*)d_out;

    char* ws = (char*)d_ws;
    size_t o = 0;
    auto alloc = [&](size_t bytes) {
        void* p = ws + o;
        o = (o + bytes + 255) & ~(size_t)255;
        return p;
    };
    int* deg = (int*)alloc(N_NODES * sizeof(int));
    int* off = (int*)alloc((N_NODES + 1) * sizeof(int));
    int* cursor = (int*)alloc(N_NODES * sizeof(int));
    int* partials = (int*)alloc(SCAN_NB * sizeof(int));
    int* csr = (int*)alloc(N_EDGES * sizeof(int));
    float* wt = (float*)alloc(3 * DIM * DIM * sizeof(float));
    float* colsum = (float*)alloc(DIM * sizeof(float));
    float* colsumsq = (float*)alloc(DIM * sizeof(float));
    float* bnsc = (float*)alloc(DIM * sizeof(float));
    float* bnsh = (float*)alloc(DIM * sizeof(float));
    float* bufA = (float*)alloc((size_t)N_NODES * DIM * sizeof(float));
    float* bufB = (float*)alloc((size_t)N_NODES * DIM * sizeof(float));

    hipMemsetAsync(deg, 0, N_NODES * sizeof(int), stream);
    hipMemsetAsync(colsum, 0, DIM * sizeof(float), stream);
    hipMemsetAsync(colsumsq, 0, DIM * sizeof(float), stream);

    hist_kernel<<<1024, 256, 0, stream>>>(ei + N_EDGES, deg);
    scan_partial_kernel<<<SCAN_NB, SCAN_BLOCK, 0, stream>>>(deg, partials);
    scan_partials_kernel<<<1, 512, 0, stream>>>(partials, off);
    scan_scatter_kernel<<<SCAN_NB, SCAN_BLOCK, 0, stream>>>(deg, partials, off, cursor);
    fill_kernel<<<1024, 256, 0, stream>>>(ei, ei + N_EDGES, cursor, csr);
    transpose_w_kernel<<<(3 * DIM * DIM + 255) / 256, 256, 0, stream>>>(Wp[0], Wp[1], Wp[2], wt);

    const float* hin = x;
    float* tbuf = bufA;
    float* ybuf = bufB;
    for (int l = 0; l < 3; ++l) {
        agg_kernel<<<2048, 256, 0, stream>>>(hin, tbuf, off, csr, eps, l);
        gemm_kernel<<<N_NODES / 32, 256, 0, stream>>>(tbuf, wt + l * DIM * DIM, bp[l], ybuf,
                                                      colsum, colsumsq);
        bnfin_kernel<<<1, DIM, 0, stream>>>(colsum, colsumsq, gamma + l * DIM, beta + l * DIM,
                                            bnsc, bnsh);
        apply_kernel<<<4096, 256, 0, stream>>>(ybuf, bnsc, bnsh, tbuf);
        hin = tbuf;
        float* tmp = tbuf; tbuf = ybuf; ybuf = tmp;
    }
    pool_kernel<<<N_GRAPHS, DIM, 0, stream>>>(hin, batch, out);
}

// Round 3
// 1090.176 us; speedup vs baseline: 1.2624x; 1.0536x over previous
//
#include <hip/hip_runtime.h>

#define N_NODES 100000
#define N_EDGES 1600000
#define DIM 128
#define N_GRAPHS 1024

#define SCAN_BLOCK 256
#define SCAN_NB ((N_NODES + SCAN_BLOCK - 1) / SCAN_BLOCK)  // 391

#define NPART 8
#define PART_SZ 12500  // N_NODES / NPART

// ---------------- CSR build (XCD-partitioned by dst range) ----------------
// blockIdx & 7 -> partition p; round-robin dispatch puts all of partition p's
// blocks on XCD p, so deg/cursor/csr lines for p's dst range are dirtied by
// ONE XCD's L2 only (kills the 16x write-back amplification seen in R2:
// WRITE_SIZE 105 MB for a 6.4 MB csr).

__global__ __launch_bounds__(256) void hist_part_kernel(const int* __restrict__ dst,
                                                        int* __restrict__ deg) {
    int p = blockIdx.x & (NPART - 1);
    int bgrp = blockIdx.x >> 3;
    int nb = gridDim.x >> 3;
    int tid = bgrp * blockDim.x + threadIdx.x;
    int nthreads = nb * blockDim.x;
    const int NE4 = N_EDGES / 4;
    for (int i = tid; i < NE4; i += nthreads) {
        int4 d4 = ((const int4*)dst)[i];
        if (d4.x / PART_SZ == p) atomicAdd(&deg[d4.x], 1);
        if (d4.y / PART_SZ == p) atomicAdd(&deg[d4.y], 1);
        if (d4.z / PART_SZ == p) atomicAdd(&deg[d4.z], 1);
        if (d4.w / PART_SZ == p) atomicAdd(&deg[d4.w], 1);
    }
}

__global__ __launch_bounds__(256) void fill_part_kernel(const int* __restrict__ src,
                                                        const int* __restrict__ dst,
                                                        int* __restrict__ cursor,
                                                        int* __restrict__ csr) {
    int p = blockIdx.x & (NPART - 1);
    int bgrp = blockIdx.x >> 3;
    int nb = gridDim.x >> 3;
    int tid = bgrp * blockDim.x + threadIdx.x;
    int nthreads = nb * blockDim.x;
    const int NE4 = N_EDGES / 4;
    for (int i = tid; i < NE4; i += nthreads) {
        int4 d4 = ((const int4*)dst)[i];
        int4 s4 = ((const int4*)src)[i];
        if (d4.x / PART_SZ == p) csr[atomicAdd(&cursor[d4.x], 1)] = s4.x;
        if (d4.y / PART_SZ == p) csr[atomicAdd(&cursor[d4.y], 1)] = s4.y;
        if (d4.z / PART_SZ == p) csr[atomicAdd(&cursor[d4.z], 1)] = s4.z;
        if (d4.w / PART_SZ == p) csr[atomicAdd(&cursor[d4.w], 1)] = s4.w;
    }
}

// pass 1: per-block sums of deg
__global__ __launch_bounds__(SCAN_BLOCK) void scan_partial_kernel(const int* __restrict__ deg,
                                                                  int* __restrict__ partials) {
    __shared__ int red[SCAN_BLOCK / 64];
    int i = blockIdx.x * SCAN_BLOCK + threadIdx.x;
    int v = (i < N_NODES) ? deg[i] : 0;
    for (int o = 32; o > 0; o >>= 1) v += __shfl_down(v, o, 64);
    if ((threadIdx.x & 63) == 0) red[threadIdx.x >> 6] = v;
    __syncthreads();
    if (threadIdx.x == 0) {
        int s = 0;
#pragma unroll
        for (int w = 0; w < SCAN_BLOCK / 64; ++w) s += red[w];
        partials[blockIdx.x] = s;
    }
}

// pass 2: exclusive-scan the 391 partials; write off[N_NODES]=total
__global__ __launch_bounds__(512) void scan_partials_kernel(int* __restrict__ partials,
                                                            int* __restrict__ off) {
    __shared__ int sm[512];
    int t = threadIdx.x;
    int v = (t < SCAN_NB) ? partials[t] : 0;
    sm[t] = v;
    __syncthreads();
    for (int o = 1; o < 512; o <<= 1) {
        int u = (t >= o) ? sm[t - o] : 0;
        __syncthreads();
        sm[t] += u;
        __syncthreads();
    }
    if (t < SCAN_NB) partials[t] = sm[t] - v;
    if (t == 0) off[N_NODES] = sm[511];
}

// pass 3: block-local exclusive scan + block offset -> off, cursor
__global__ __launch_bounds__(SCAN_BLOCK) void scan_scatter_kernel(const int* __restrict__ deg,
                                                                  const int* __restrict__ partials,
                                                                  int* __restrict__ off,
                                                                  int* __restrict__ cursor) {
    __shared__ int sm[SCAN_BLOCK];
    int t = threadIdx.x;
    int i = blockIdx.x * SCAN_BLOCK + t;
    int v = (i < N_NODES) ? deg[i] : 0;
    sm[t] = v;
    __syncthreads();
    for (int o = 1; o < SCAN_BLOCK; o <<= 1) {
        int u = (t >= o) ? sm[t - o] : 0;
        __syncthreads();
        sm[t] += u;
        __syncthreads();
    }
    if (i < N_NODES) {
        int r = partials[blockIdx.x] + sm[t] - v;
        off[i] = r;
        cursor[i] = r;
    }
}

// ---------------- W transpose (wt[l][k][d] = Wl[d][k]) ----------------

__global__ void transpose_w_kernel(const float* __restrict__ W1, const float* __restrict__ W2,
                                   const float* __restrict__ W3, float* __restrict__ wt) {
    int i = blockIdx.x * blockDim.x + threadIdx.x;
    if (i >= 3 * DIM * DIM) return;
    int l = i / (DIM * DIM);
    int r = i % (DIM * DIM);
    int d = r >> 7, k = r & 127;
    const float* W = (l == 0) ? W1 : (l == 1) ? W2 : W3;
    wt[l * DIM * DIM + k * DIM + d] = W[d * DIM + k];
}

// ---------------- aggregation: t[n] = (1+eps)*h[n] + sum_{s in N(n)} h[s] ----------------

__global__ __launch_bounds__(256) void agg_kernel(const float* __restrict__ hin, float* __restrict__ t,
                                                  const int* __restrict__ off, const int* __restrict__ csr,
                                                  const float* __restrict__ eps_arr, int layer) {
    int gtid = blockIdx.x * blockDim.x + threadIdx.x;
    int grp = gtid >> 5;
    int lane = threadIdx.x & 31;
    int ngrp = (gridDim.x * blockDim.x) >> 5;
    float se = 1.0f + eps_arr[layer];
    for (int n = grp; n < N_NODES; n += ngrp) {
        float4 v = ((const float4*)(hin + (size_t)n * DIM))[lane];
        float ax = v.x * se, ay = v.y * se, az = v.z * se, aw = v.w * se;
        int k = off[n], e = off[n + 1];
        for (; k + 3 < e; k += 4) {
            int s0 = csr[k], s1 = csr[k + 1], s2 = csr[k + 2], s3 = csr[k + 3];
            float4 a = ((const float4*)(hin + (size_t)s0 * DIM))[lane];
            float4 b = ((const float4*)(hin + (size_t)s1 * DIM))[lane];
            float4 c = ((const float4*)(hin + (size_t)s2 * DIM))[lane];
            float4 d = ((const float4*)(hin + (size_t)s3 * DIM))[lane];
            ax += (a.x + b.x) + (c.x + d.x);
            ay += (a.y + b.y) + (c.y + d.y);
            az += (a.z + b.z) + (c.z + d.z);
            aw += (a.w + b.w) + (c.w + d.w);
        }
        for (; k < e; ++k) {
            int s0 = csr[k];
            float4 a = ((const float4*)(hin + (size_t)s0 * DIM))[lane];
            ax += a.x; ay += a.y; az += a.z; aw += a.w;
        }
        float4 o;
        o.x = ax; o.y = ay; o.z = az; o.w = aw;
        ((float4*)(t + (size_t)n * DIM))[lane] = o;
    }
}

// ---------------- GEMM: y = t @ W^T + b, fused per-column sum/sumsq ----------------

__global__ __launch_bounds__(256) void gemm_kernel(const float* __restrict__ t, const float* __restrict__ wt,
                                                   const float* __restrict__ bias, float* __restrict__ y,
                                                   float* __restrict__ colsum, float* __restrict__ colsumsq) {
    __shared__ float sred[2 * 8 * DIM];
    int tid = threadIdx.x;
    int d0 = (tid & 31) * 4;
    int g = tid >> 5;
    int row0 = blockIdx.x * 32 + g * 4;
    float acc[4][4] = {{0.0f}};
    for (int k = 0; k < DIM; k += 4) {
        float4 w0 = *(const float4*)(wt + (k + 0) * DIM + d0);
        float4 w1 = *(const float4*)(wt + (k + 1) * DIM + d0);
        float4 w2 = *(const float4*)(wt + (k + 2) * DIM + d0);
        float4 w3 = *(const float4*)(wt + (k + 3) * DIM + d0);
#pragma unroll
        for (int i = 0; i < 4; ++i) {
            float4 tv = *(const float4*)(t + (size_t)(row0 + i) * DIM + k);
            acc[i][0] += tv.x * w0.x + tv.y * w1.x + tv.z * w2.x + tv.w * w3.x;
            acc[i][1] += tv.x * w0.y + tv.y * w1.y + tv.z * w2.y + tv.w * w3.y;
            acc[i][2] += tv.x * w0.z + tv.y * w1.z + tv.z * w2.z + tv.w * w3.z;
            acc[i][3] += tv.x * w0.w + tv.y * w1.w + tv.z * w2.w + tv.w * w3.w;
        }
    }
    float4 bv = *(const float4*)(bias + d0);
    float ps[4] = {0, 0, 0, 0}, pq[4] = {0, 0, 0, 0};
#pragma unroll
    for (int i = 0; i < 4; ++i) {
        acc[i][0] += bv.x; acc[i][1] += bv.y; acc[i][2] += bv.z; acc[i][3] += bv.w;
        float4 o;
        o.x = acc[i][0]; o.y = acc[i][1]; o.z = acc[i][2]; o.w = acc[i][3];
        *(float4*)(y + (size_t)(row0 + i) * DIM + d0) = o;
#pragma unroll
        for (int j = 0; j < 4; ++j) {
            ps[j] += acc[i][j];
            pq[j] += acc[i][j] * acc[i][j];
        }
    }
#pragma unroll
    for (int j = 0; j < 4; ++j) {
        sred[g * DIM + d0 + j] = ps[j];
        sred[8 * DIM + g * DIM + d0 + j] = pq[j];
    }
    __syncthreads();
    if (tid < DIM) {
        float s = 0.0f, q = 0.0f;
#pragma unroll
        for (int g2 = 0; g2 < 8; ++g2) {
            s += sred[g2 * DIM + tid];
            q += sred[8 * DIM + g2 * DIM + tid];
        }
        atomicAdd(&colsum[tid], s);
        atomicAdd(&colsumsq[tid], q);
    }
}

// ---------------- BN finalize ----------------

__global__ void bnfin_kernel(float* __restrict__ colsum, float* __restrict__ colsumsq,
                             const float* __restrict__ gamma, const float* __restrict__ beta,
                             float* __restrict__ scale, float* __restrict__ shift) {
    int d = threadIdx.x;
    float m = colsum[d] * (1.0f / N_NODES);
    float v = colsumsq[d] * (1.0f / N_NODES) - m * m;
    float sc = gamma[d] * rsqrtf(v + 1e-5f);
    scale[d] = sc;
    shift[d] = beta[d] - m * sc;
    colsum[d] = 0.0f;
    colsumsq[d] = 0.0f;
}

// ---------------- BN apply + ReLU ----------------

__global__ __launch_bounds__(256) void apply_kernel(const float* __restrict__ y,
                                                    const float* __restrict__ scale,
                                                    const float* __restrict__ shift,
                                                    float* __restrict__ h) {
    int i = blockIdx.x * blockDim.x + threadIdx.x;
    int stride = gridDim.x * blockDim.x;
    const int TOT = N_NODES * DIM / 4;
    for (; i < TOT; i += stride) {
        int d0 = (i * 4) & 127;
        float4 v = ((const float4*)y)[i];
        float4 sc = *(const float4*)(scale + d0);
        float4 sh = *(const float4*)(shift + d0);
        float4 o;
        o.x = fmaxf(v.x * sc.x + sh.x, 0.0f);
        o.y = fmaxf(v.y * sc.y + sh.y, 0.0f);
        o.z = fmaxf(v.z * sc.z + sh.z, 0.0f);
        o.w = fmaxf(v.w * sc.w + sh.w, 0.0f);
        ((float4*)h)[i] = o;
    }
}

// ---------------- global mean pool (batch sorted) ----------------

__global__ __launch_bounds__(128) void pool_kernel(const float* __restrict__ h,
                                                   const int* __restrict__ batch,
                                                   float* __restrict__ out) {
    int gph = blockIdx.x;
    int d = threadIdx.x;
    int lo = 0, hi = N_NODES;
    while (lo < hi) {
        int mid = (lo + hi) >> 1;
        if (batch[mid] < gph) lo = mid + 1; else hi = mid;
    }
    int start = lo;
    hi = N_NODES;
    while (lo < hi) {
        int mid = (lo + hi) >> 1;
        if (batch[mid] < gph + 1) lo = mid + 1; else hi = mid;
    }
    int end = lo;
    float s = 0.0f;
    for (int n = start; n < end; ++n) s += h[(size_t)n * DIM + d];
    out[gph * DIM + d] = s / fmaxf((float)(end - start), 1.0f);
}

// ---------------- launch ----------------

extern "C" void kernel_launch(void* const* d_in, const int* in_sizes, int n_in,
                              void* d_out, int out_size, void* d_ws, size_t ws_size,
                              hipStream_t stream) {
    const float* x = (const float*)d_in[0];
    const int* ei = (const int*)d_in[1];
    const int* batch = (const int*)d_in[2];
    const float* Wp[3] = {(const float*)d_in[3], (const float*)d_in[5], (const float*)d_in[7]};
    const float* bp[3] = {(const float*)d_in[4], (const float*)d_in[6], (const float*)d_in[8]};
    const float* eps = (const float*)d_in[9];
    const float* gamma = (const float*)d_in[10];
    const float* beta = (const float*)d_in[11];
    float* out = (float*)d_out;

    char* ws = (char*)d_ws;
    size_t o = 0;
    auto alloc = [&](size_t bytes) {
        void* p = ws + o;
        o = (o + bytes + 255) & ~(size_t)255;
        return p;
    };
    int* deg = (int*)alloc(N_NODES * sizeof(int));
    int* off = (int*)alloc((N_NODES + 1) * sizeof(int));
    int* cursor = (int*)alloc(N_NODES * sizeof(int));
    int* partials = (int*)alloc(SCAN_NB * sizeof(int));
    int* csr = (int*)alloc(N_EDGES * sizeof(int));
    float* wt = (float*)alloc(3 * DIM * DIM * sizeof(float));
    float* colsum = (float*)alloc(DIM * sizeof(float));
    float* colsumsq = (float*)alloc(DIM * sizeof(float));
    float* bnsc = (float*)alloc(DIM * sizeof(float));
    float* bnsh = (float*)alloc(DIM * sizeof(float));
    float* bufA = (float*)alloc((size_t)N_NODES * DIM * sizeof(float));
    float* bufB = (float*)alloc((size_t)N_NODES * DIM * sizeof(float));

    hipMemsetAsync(deg, 0, N_NODES * sizeof(int), stream);
    hipMemsetAsync(colsum, 0, DIM * sizeof(float), stream);
    hipMemsetAsync(colsumsq, 0, DIM * sizeof(float), stream);

    hist_part_kernel<<<1024, 256, 0, stream>>>(ei + N_EDGES, deg);
    scan_partial_kernel<<<SCAN_NB, SCAN_BLOCK, 0, stream>>>(deg, partials);
    scan_partials_kernel<<<1, 512, 0, stream>>>(partials, off);
    scan_scatter_kernel<<<SCAN_NB, SCAN_BLOCK, 0, stream>>>(deg, partials, off, cursor);
    fill_part_kernel<<<1024, 256, 0, stream>>>(ei, ei + N_EDGES, cursor, csr);
    transpose_w_kernel<<<(3 * DIM * DIM + 255) / 256, 256, 0, stream>>>(Wp[0], Wp[1], Wp[2], wt);

    const float* hin = x;
    float* tbuf = bufA;
    float* ybuf = bufB;
    for (int l = 0; l < 3; ++l) {
        agg_kernel<<<2048, 256, 0, stream>>>(hin, tbuf, off, csr, eps, l);
        gemm_kernel<<<N_NODES / 32, 256, 0, stream>>>(tbuf, wt + l * DIM * DIM, bp[l], ybuf,
                                                      colsum, colsumsq);
        bnfin_kernel<<<1, DIM, 0, stream>>>(colsum, colsumsq, gamma + l * DIM, beta + l * DIM,
                                            bnsc, bnsh);
        apply_kernel<<<4096, 256, 0, stream>>>(ybuf, bnsc, bnsh, tbuf);
        hin = tbuf;
        float* tmp = tbuf; tbuf = ybuf; ybuf = tmp;
    }
    pool_kernel<<<N_GRAPHS, DIM, 0, stream>>>(hin, batch, out);
}

// Round 5
// 882.219 us; speedup vs baseline: 1.5599x; 1.2357x over previous
//
#include <hip/hip_runtime.h>

#define N_NODES 100000
#define N_PAD 100032   // 1563 * 64 — zero-padded rows so MFMA GEMM needs no tail masking
#define N_EDGES 1600000
#define DIM 128
#define N_GRAPHS 1024

#define SCAN_BLOCK 256
#define SCAN_NB ((N_NODES + SCAN_BLOCK - 1) / SCAN_BLOCK)  // 391

#define NPART 8
#define PART_SZ 12500

typedef __bf16 bf16x8 __attribute__((ext_vector_type(8)));
typedef float f32x4 __attribute__((ext_vector_type(4)));

__device__ __forceinline__ unsigned short f2bf(float f) {
    unsigned u = __builtin_bit_cast(unsigned, f);
    u += 0x7fffu + ((u >> 16) & 1u);  // RNE
    return (unsigned short)(u >> 16);
}
__device__ __forceinline__ unsigned pk2(float a, float b) {
    return (unsigned)f2bf(a) | ((unsigned)f2bf(b) << 16);
}

// ---------------- CSR build (XCD-partitioned by dst range) ----------------

__global__ __launch_bounds__(256) void hist_part_kernel(const int* __restrict__ dst,
                                                        int* __restrict__ deg) {
    int p = blockIdx.x & (NPART - 1);
    int bgrp = blockIdx.x >> 3;
    int nb = gridDim.x >> 3;
    int tid = bgrp * blockDim.x + threadIdx.x;
    int nthreads = nb * blockDim.x;
    const int NE4 = N_EDGES / 4;
    for (int i = tid; i < NE4; i += nthreads) {
        int4 d4 = ((const int4*)dst)[i];
        if (d4.x / PART_SZ == p) atomicAdd(&deg[d4.x], 1);
        if (d4.y / PART_SZ == p) atomicAdd(&deg[d4.y], 1);
        if (d4.z / PART_SZ == p) atomicAdd(&deg[d4.z], 1);
        if (d4.w / PART_SZ == p) atomicAdd(&deg[d4.w], 1);
    }
}

__global__ __launch_bounds__(256) void fill_part_kernel(const int* __restrict__ src,
                                                        const int* __restrict__ dst,
                                                        int* __restrict__ cursor,
                                                        int* __restrict__ csr) {
    int p = blockIdx.x & (NPART - 1);
    int bgrp = blockIdx.x >> 3;
    int nb = gridDim.x >> 3;
    int tid = bgrp * blockDim.x + threadIdx.x;
    int nthreads = nb * blockDim.x;
    const int NE4 = N_EDGES / 4;
    for (int i = tid; i < NE4; i += nthreads) {
        int4 d4 = ((const int4*)dst)[i];
        int4 s4 = ((const int4*)src)[i];
        if (d4.x / PART_SZ == p) csr[atomicAdd(&cursor[d4.x], 1)] = s4.x;
        if (d4.y / PART_SZ == p) csr[atomicAdd(&cursor[d4.y], 1)] = s4.y;
        if (d4.z / PART_SZ == p) csr[atomicAdd(&cursor[d4.z], 1)] = s4.z;
        if (d4.w / PART_SZ == p) csr[atomicAdd(&cursor[d4.w], 1)] = s4.w;
    }
}

// ---------------- hierarchical scan ----------------

__global__ __launch_bounds__(SCAN_BLOCK) void scan_partial_kernel(const int* __restrict__ deg,
                                                                  int* __restrict__ partials) {
    __shared__ int red[SCAN_BLOCK / 64];
    int i = blockIdx.x * SCAN_BLOCK + threadIdx.x;
    int v = (i < N_NODES) ? deg[i] : 0;
    for (int o = 32; o > 0; o >>= 1) v += __shfl_down(v, o, 64);
    if ((threadIdx.x & 63) == 0) red[threadIdx.x >> 6] = v;
    __syncthreads();
    if (threadIdx.x == 0) {
        int s = 0;
#pragma unroll
        for (int w = 0; w < SCAN_BLOCK / 64; ++w) s += red[w];
        partials[blockIdx.x] = s;
    }
}

__global__ __launch_bounds__(512) void scan_partials_kernel(int* __restrict__ partials,
                                                            int* __restrict__ off) {
    __shared__ int sm[512];
    int t = threadIdx.x;
    int v = (t < SCAN_NB) ? partials[t] : 0;
    sm[t] = v;
    __syncthreads();
    for (int o = 1; o < 512; o <<= 1) {
        int u = (t >= o) ? sm[t - o] : 0;
        __syncthreads();
        sm[t] += u;
        __syncthreads();
    }
    if (t < SCAN_NB) partials[t] = sm[t] - v;
    if (t == 0) off[N_NODES] = sm[511];
}

__global__ __launch_bounds__(SCAN_BLOCK) void scan_scatter_kernel(const int* __restrict__ deg,
                                                                  const int* __restrict__ partials,
                                                                  int* __restrict__ off,
                                                                  int* __restrict__ cursor) {
    __shared__ int sm[SCAN_BLOCK];
    int t = threadIdx.x;
    int i = blockIdx.x * SCAN_BLOCK + t;
    int v = (i < N_NODES) ? deg[i] : 0;
    sm[t] = v;
    __syncthreads();
    for (int o = 1; o < SCAN_BLOCK; o <<= 1) {
        int u = (t >= o) ? sm[t - o] : 0;
        __syncthreads();
        sm[t] += u;
        __syncthreads();
    }
    if (i < N_NODES) {
        int r = partials[blockIdx.x] + sm[t] - v;
        off[i] = r;
        cursor[i] = r;
    }
}

// ---------------- W -> bf16 B-fragment layout ----------------
// wb[l][nt][kk][lane][j] = bf16( W_l[nt*16 + (lane&15)][kk*32 + (lane>>4)*8 + j] )
// so gemm's B-frag load is one coalesced 16B/lane read.

__global__ __launch_bounds__(64) void wprep_kernel(const float* __restrict__ W1,
                                                   const float* __restrict__ W2,
                                                   const float* __restrict__ W3,
                                                   uint4* __restrict__ wb4) {
    int b = blockIdx.x;           // 0..95: l*32 + nt*4 + kk
    int l = b >> 5;
    int nt = (b >> 2) & 7;
    int kk = b & 3;
    int lane = threadIdx.x;
    const float* W = (l == 0) ? W1 : (l == 1) ? W2 : W3;
    int row = nt * 16 + (lane & 15);
    int cb = kk * 32 + (lane >> 4) * 8;
    const float* g = W + row * DIM + cb;
    float4 f0 = *(const float4*)g;
    float4 f1 = *(const float4*)(g + 4);
    uint4 o;
    o.x = pk2(f0.x, f0.y);
    o.y = pk2(f0.z, f0.w);
    o.z = pk2(f1.x, f1.y);
    o.w = pk2(f1.z, f1.w);
    wb4[(size_t)b * 64 + lane] = o;
}

// ---------------- aggregation: t[n] = (1+eps)*h[n] + sum_{s in N(n)} h[s] ----------------

__global__ __launch_bounds__(256) void agg_kernel(const float* __restrict__ hin, float* __restrict__ t,
                                                  const int* __restrict__ off, const int* __restrict__ csr,
                                                  const float* __restrict__ eps_arr, int layer) {
    int gtid = blockIdx.x * blockDim.x + threadIdx.x;
    int grp = gtid >> 5;
    int lane = threadIdx.x & 31;
    int ngrp = (gridDim.x * blockDim.x) >> 5;
    float se = 1.0f + eps_arr[layer];
    for (int n = grp; n < N_NODES; n += ngrp) {
        float4 v = ((const float4*)(hin + (size_t)n * DIM))[lane];
        float ax = v.x * se, ay = v.y * se, az = v.z * se, aw = v.w * se;
        int k = off[n], e = off[n + 1];
        for (; k + 3 < e; k += 4) {
            int s0 = csr[k], s1 = csr[k + 1], s2 = csr[k + 2], s3 = csr[k + 3];
            float4 a = ((const float4*)(hin + (size_t)s0 * DIM))[lane];
            float4 b = ((const float4*)(hin + (size_t)s1 * DIM))[lane];
            float4 c = ((const float4*)(hin + (size_t)s2 * DIM))[lane];
            float4 d = ((const float4*)(hin + (size_t)s3 * DIM))[lane];
            ax += (a.x + b.x) + (c.x + d.x);
            ay += (a.y + b.y) + (c.y + d.y);
            az += (a.z + b.z) + (c.z + d.z);
            aw += (a.w + b.w) + (c.w + d.w);
        }
        for (; k < e; ++k) {
            int s0 = csr[k];
            float4 a = ((const float4*)(hin + (size_t)s0 * DIM))[lane];
            ax += a.x; ay += a.y; az += a.z; aw += a.w;
        }
        float4 o;
        o.x = ax; o.y = ay; o.z = az; o.w = aw;
        ((float4*)(t + (size_t)n * DIM))[lane] = o;
    }
}

// ---------------- MFMA GEMM: y = T @ W^T (bias dropped: BN-mean cancels it) ---------
// block: 256 thr = 4 waves, 64 rows. T staged to LDS as bf16, XOR-swizzled
// (^((row&7)<<4)) so ds_read_b128 of 16 rows is 2-way bank aliasing (free).
// Stats (colsum/colsumsq) fused; pad rows are zero -> contribute nothing.

__global__ __launch_bounds__(256) void gemm_mfma_kernel(const float* __restrict__ t,
                                                        const uint4* __restrict__ wb4,
                                                        float* __restrict__ y,
                                                        float* __restrict__ colsum,
                                                        float* __restrict__ colsumsq) {
    __shared__ unsigned short tile[64 * DIM];  // bf16, swizzled
    __shared__ float sstat[4][DIM];
    __shared__ float sstatq[4][DIM];
    int tid = threadIdx.x;
    int row0 = blockIdx.x * 64;

    // stage 64x128 f32 -> bf16 LDS (4 16B-slots per thread, coalesced global reads)
#pragma unroll
    for (int j = 0; j < 4; ++j) {
        int idx = tid + j * 256;       // 0..1023
        int row = idx >> 4;
        int ks = idx & 15;
        const float* g = t + (size_t)(row0 + row) * DIM + ks * 8;
        float4 f0 = *(const float4*)g;
        float4 f1 = *(const float4*)(g + 4);
        uint4 o;
        o.x = pk2(f0.x, f0.y);
        o.y = pk2(f0.z, f0.w);
        o.z = pk2(f1.x, f1.y);
        o.w = pk2(f1.z, f1.w);
        int byte = (row * 256 + ks * 16) ^ ((row & 7) << 4);
        *(uint4*)((char*)tile + byte) = o;
    }
    __syncthreads();

    int w = tid >> 6;
    int l = tid & 63;
    int lr = l & 15;      // A row / D col
    int lg = l >> 4;      // k-group / D row-group
    bf16x8 a[4];
#pragma unroll
    for (int kk = 0; kk < 4; ++kk) {
        int row = w * 16 + lr;
        int byte = (row * 256 + kk * 64 + lg * 16) ^ ((row & 7) << 4);
        a[kk] = __builtin_bit_cast(bf16x8, *(uint4*)((char*)tile + byte));
    }

#pragma unroll
    for (int nt = 0; nt < 8; ++nt) {
        f32x4 acc = {0.0f, 0.0f, 0.0f, 0.0f};
#pragma unroll
        for (int kk = 0; kk < 4; ++kk) {
            bf16x8 b = __builtin_bit_cast(bf16x8, wb4[(nt * 4 + kk) * 64 + l]);
            acc = __builtin_amdgcn_mfma_f32_16x16x32_bf16(a[kk], b, acc, 0, 0, 0);
        }
        int col = nt * 16 + lr;
        size_t base = (size_t)(row0 + w * 16 + lg * 4) * DIM + col;
        y[base] = acc[0];
        y[base + DIM] = acc[1];
        y[base + 2 * DIM] = acc[2];
        y[base + 3 * DIM] = acc[3];
        float s = acc[0] + acc[1] + acc[2] + acc[3];
        float q = acc[0] * acc[0] + acc[1] * acc[1] + acc[2] * acc[2] + acc[3] * acc[3];
        s += __shfl_xor(s, 16);
        s += __shfl_xor(s, 32);
        q += __shfl_xor(q, 16);
        q += __shfl_xor(q, 32);
        if (lg == 0) {
            sstat[w][col] = s;
            sstatq[w][col] = q;
        }
    }
    __syncthreads();
    if (tid < DIM) {
        float s = sstat[0][tid] + sstat[1][tid] + sstat[2][tid] + sstat[3][tid];
        float q = sstatq[0][tid] + sstatq[1][tid] + sstatq[2][tid] + sstatq[3][tid];
        atomicAdd(&colsum[tid], s);
        atomicAdd(&colsumsq[tid], q);
    }
}

// ---------------- BN finalize (bias-free; BN subtracts it exactly) ----------------

__global__ void bnfin_kernel(float* __restrict__ colsum, float* __restrict__ colsumsq,
                             const float* __restrict__ gamma, const float* __restrict__ beta,
                             float* __restrict__ scale, float* __restrict__ shift) {
    int d = threadIdx.x;
    float m = colsum[d] * (1.0f / N_NODES);
    float v = colsumsq[d] * (1.0f / N_NODES) - m * m;
    float sc = gamma[d] * rsqrtf(v + 1e-5f);
    scale[d] = sc;
    shift[d] = beta[d] - m * sc;
    colsum[d] = 0.0f;
    colsumsq[d] = 0.0f;
}

// ---------------- BN apply + ReLU ----------------

__global__ __launch_bounds__(256) void apply_kernel(const float* __restrict__ y,
                                                    const float* __restrict__ scale,
                                                    const float* __restrict__ shift,
                                                    float* __restrict__ h) {
    int i = blockIdx.x * blockDim.x + threadIdx.x;
    int stride = gridDim.x * blockDim.x;
    const int TOT = N_NODES * DIM / 4;
    for (; i < TOT; i += stride) {
        int d0 = (i * 4) & 127;
        float4 v = ((const float4*)y)[i];
        float4 sc = *(const float4*)(scale + d0);
        float4 sh = *(const float4*)(shift + d0);
        float4 o;
        o.x = fmaxf(v.x * sc.x + sh.x, 0.0f);
        o.y = fmaxf(v.y * sc.y + sh.y, 0.0f);
        o.z = fmaxf(v.z * sc.z + sh.z, 0.0f);
        o.w = fmaxf(v.w * sc.w + sh.w, 0.0f);
        ((float4*)h)[i] = o;
    }
}

// ---------------- global mean pool (batch sorted) ----------------

__global__ __launch_bounds__(128) void pool_kernel(const float* __restrict__ h,
                                                   const int* __restrict__ batch,
                                                   float* __restrict__ out) {
    int gph = blockIdx.x;
    int d = threadIdx.x;
    int lo = 0, hi = N_NODES;
    while (lo < hi) {
        int mid = (lo + hi) >> 1;
        if (batch[mid] < gph) lo = mid + 1; else hi = mid;
    }
    int start = lo;
    hi = N_NODES;
    while (lo < hi) {
        int mid = (lo + hi) >> 1;
        if (batch[mid] < gph + 1) lo = mid + 1; else hi = mid;
    }
    int end = lo;
    float s = 0.0f;
    for (int n = start; n < end; ++n) s += h[(size_t)n * DIM + d];
    out[gph * DIM + d] = s / fmaxf((float)(end - start), 1.0f);
}

// ---------------- launch ----------------

extern "C" void kernel_launch(void* const* d_in, const int* in_sizes, int n_in,
                              void* d_out, int out_size, void* d_ws, size_t ws_size,
                              hipStream_t stream) {
    const float* x = (const float*)d_in[0];
    const int* ei = (const int*)d_in[1];
    const int* batch = (const int*)d_in[2];
    const float* Wp[3] = {(const float*)d_in[3], (const float*)d_in[5], (const float*)d_in[7]};
    const float* eps = (const float*)d_in[9];
    const float* gamma = (const float*)d_in[10];
    const float* beta = (const float*)d_in[11];
    float* out = (float*)d_out;

    char* ws = (char*)d_ws;
    size_t o = 0;
    auto alloc = [&](size_t bytes) {
        void* p = ws + o;
        o = (o + bytes + 255) & ~(size_t)255;
        return p;
    };
    int* deg = (int*)alloc(N_NODES * sizeof(int));
    int* off = (int*)alloc((N_NODES + 1) * sizeof(int));
    int* cursor = (int*)alloc(N_NODES * sizeof(int));
    int* partials = (int*)alloc(SCAN_NB * sizeof(int));
    int* csr = (int*)alloc(N_EDGES * sizeof(int));
    uint4* wb4 = (uint4*)alloc(3 * 8 * 4 * 64 * 16);  // 96 KB bf16 B-fragments
    float* colsum = (float*)alloc(DIM * sizeof(float));
    float* colsumsq = (float*)alloc(DIM * sizeof(float));
    float* bnsc = (float*)alloc(DIM * sizeof(float));
    float* bnsh = (float*)alloc(DIM * sizeof(float));
    float* bufA = (float*)alloc((size_t)N_PAD * DIM * sizeof(float));
    float* bufB = (float*)alloc((size_t)N_PAD * DIM * sizeof(float));

    hipMemsetAsync(deg, 0, N_NODES * sizeof(int), stream);
    hipMemsetAsync(colsum, 0, DIM * sizeof(float), stream);
    hipMemsetAsync(colsumsq, 0, DIM * sizeof(float), stream);
    // zero pad rows so they contribute nothing to GEMM output/stats
    hipMemsetAsync(bufA + (size_t)N_NODES * DIM, 0, (size_t)(N_PAD - N_NODES) * DIM * sizeof(float), stream);
    hipMemsetAsync(bufB + (size_t)N_NODES * DIM, 0, (size_t)(N_PAD - N_NODES) * DIM * sizeof(float), stream);

    hist_part_kernel<<<1024, 256, 0, stream>>>(ei + N_EDGES, deg);
    scan_partial_kernel<<<SCAN_NB, SCAN_BLOCK, 0, stream>>>(deg, partials);
    scan_partials_kernel<<<1, 512, 0, stream>>>(partials, off);
    scan_scatter_kernel<<<SCAN_NB, SCAN_BLOCK, 0, stream>>>(deg, partials, off, cursor);
    fill_part_kernel<<<1024, 256, 0, stream>>>(ei, ei + N_EDGES, cursor, csr);
    wprep_kernel<<<96, 64, 0, stream>>>(Wp[0], Wp[1], Wp[2], wb4);

    const float* hin = x;
    float* tbuf = bufA;
    float* ybuf = bufB;
    for (int l = 0; l < 3; ++l) {
        agg_kernel<<<2048, 256, 0, stream>>>(hin, tbuf, off, csr, eps, l);
        gemm_mfma_kernel<<<N_PAD / 64, 256, 0, stream>>>(tbuf, wb4 + (size_t)l * 2048, ybuf,
                                                         colsum, colsumsq);
        bnfin_kernel<<<1, DIM, 0, stream>>>(colsum, colsumsq, gamma + l * DIM, beta + l * DIM,
                                            bnsc, bnsh);
        apply_kernel<<<4096, 256, 0, stream>>>(ybuf, bnsc, bnsh, tbuf);
        hin = tbuf;
        float* tmp = tbuf; tbuf = ybuf; ybuf = tmp;
    }
    pool_kernel<<<N_GRAPHS, DIM, 0, stream>>>(hin, batch, out);
}

// Round 6
// 656.131 us; speedup vs baseline: 2.0974x; 1.3446x over previous
//
#include <hip/hip_runtime.h>

#define N_NODES 100000
#define N_PAD 100032   // 1563 * 64
#define N_EDGES 1600000
#define DIM 128
#define N_GRAPHS 1024

#define SCAN_BLOCK 256
#define SCAN_NB ((N_NODES + SCAN_BLOCK - 1) / SCAN_BLOCK)  // 391

#define NPART 8
#define PART_SZ 12500

typedef __bf16 bf16x8 __attribute__((ext_vector_type(8)));
typedef float f32x4 __attribute__((ext_vector_type(4)));

__device__ __forceinline__ unsigned short f2bf(float f) {
    unsigned u = __builtin_bit_cast(unsigned, f);
    u += 0x7fffu + ((u >> 16) & 1u);  // RNE
    return (unsigned short)(u >> 16);
}
__device__ __forceinline__ unsigned pk2(float a, float b) {
    return (unsigned)f2bf(a) | ((unsigned)f2bf(b) << 16);
}
__device__ __forceinline__ float bf2f(unsigned short s) {
    return __builtin_bit_cast(float, (unsigned)s << 16);
}
// decode 4 consecutive bf16 (as uint2) -> 4 f32; odd elems need no shift
__device__ __forceinline__ void dec4(uint2 p, float& e0, float& e1, float& e2, float& e3) {
    e0 = __builtin_bit_cast(float, p.x << 16);
    e1 = __builtin_bit_cast(float, p.x & 0xffff0000u);
    e2 = __builtin_bit_cast(float, p.y << 16);
    e3 = __builtin_bit_cast(float, p.y & 0xffff0000u);
}

// ---------------- CSR build (XCD-partitioned by dst range) ----------------

__global__ __launch_bounds__(256) void hist_part_kernel(const int* __restrict__ dst,
                                                        int* __restrict__ deg) {
    int p = blockIdx.x & (NPART - 1);
    int bgrp = blockIdx.x >> 3;
    int nb = gridDim.x >> 3;
    int tid = bgrp * blockDim.x + threadIdx.x;
    int nthreads = nb * blockDim.x;
    const int NE4 = N_EDGES / 4;
    for (int i = tid; i < NE4; i += nthreads) {
        int4 d4 = ((const int4*)dst)[i];
        if (d4.x / PART_SZ == p) atomicAdd(&deg[d4.x], 1);
        if (d4.y / PART_SZ == p) atomicAdd(&deg[d4.y], 1);
        if (d4.z / PART_SZ == p) atomicAdd(&deg[d4.z], 1);
        if (d4.w / PART_SZ == p) atomicAdd(&deg[d4.w], 1);
    }
}

__global__ __launch_bounds__(256) void fill_part_kernel(const int* __restrict__ src,
                                                        const int* __restrict__ dst,
                                                        int* __restrict__ cursor,
                                                        int* __restrict__ csr) {
    int p = blockIdx.x & (NPART - 1);
    int bgrp = blockIdx.x >> 3;
    int nb = gridDim.x >> 3;
    int tid = bgrp * blockDim.x + threadIdx.x;
    int nthreads = nb * blockDim.x;
    const int NE4 = N_EDGES / 4;
    for (int i = tid; i < NE4; i += nthreads) {
        int4 d4 = ((const int4*)dst)[i];
        int4 s4 = ((const int4*)src)[i];
        if (d4.x / PART_SZ == p) csr[atomicAdd(&cursor[d4.x], 1)] = s4.x;
        if (d4.y / PART_SZ == p) csr[atomicAdd(&cursor[d4.y], 1)] = s4.y;
        if (d4.z / PART_SZ == p) csr[atomicAdd(&cursor[d4.z], 1)] = s4.z;
        if (d4.w / PART_SZ == p) csr[atomicAdd(&cursor[d4.w], 1)] = s4.w;
    }
}

// ---------------- hierarchical scan ----------------

__global__ __launch_bounds__(SCAN_BLOCK) void scan_partial_kernel(const int* __restrict__ deg,
                                                                  int* __restrict__ partials) {
    __shared__ int red[SCAN_BLOCK / 64];
    int i = blockIdx.x * SCAN_BLOCK + threadIdx.x;
    int v = (i < N_NODES) ? deg[i] : 0;
    for (int o = 32; o > 0; o >>= 1) v += __shfl_down(v, o, 64);
    if ((threadIdx.x & 63) == 0) red[threadIdx.x >> 6] = v;
    __syncthreads();
    if (threadIdx.x == 0) {
        int s = 0;
#pragma unroll
        for (int w = 0; w < SCAN_BLOCK / 64; ++w) s += red[w];
        partials[blockIdx.x] = s;
    }
}

__global__ __launch_bounds__(512) void scan_partials_kernel(int* __restrict__ partials,
                                                            int* __restrict__ off) {
    __shared__ int sm[512];
    int t = threadIdx.x;
    int v = (t < SCAN_NB) ? partials[t] : 0;
    sm[t] = v;
    __syncthreads();
    for (int o = 1; o < 512; o <<= 1) {
        int u = (t >= o) ? sm[t - o] : 0;
        __syncthreads();
        sm[t] += u;
        __syncthreads();
    }
    if (t < SCAN_NB) partials[t] = sm[t] - v;
    if (t == 0) off[N_NODES] = sm[511];
}

__global__ __launch_bounds__(SCAN_BLOCK) void scan_scatter_kernel(const int* __restrict__ deg,
                                                                  const int* __restrict__ partials,
                                                                  int* __restrict__ off,
                                                                  int* __restrict__ cursor) {
    __shared__ int sm[SCAN_BLOCK];
    int t = threadIdx.x;
    int i = blockIdx.x * SCAN_BLOCK + t;
    int v = (i < N_NODES) ? deg[i] : 0;
    sm[t] = v;
    __syncthreads();
    for (int o = 1; o < SCAN_BLOCK; o <<= 1) {
        int u = (t >= o) ? sm[t - o] : 0;
        __syncthreads();
        sm[t] += u;
        __syncthreads();
    }
    if (i < N_NODES) {
        int r = partials[blockIdx.x] + sm[t] - v;
        off[i] = r;
        cursor[i] = r;
    }
}

// ---------------- W -> bf16 B-fragment layout (verified in R5) ----------------

__global__ __launch_bounds__(64) void wprep_kernel(const float* __restrict__ W1,
                                                   const float* __restrict__ W2,
                                                   const float* __restrict__ W3,
                                                   uint4* __restrict__ wb4) {
    int b = blockIdx.x;           // l*32 + nt*4 + kk
    int l = b >> 5;
    int nt = (b >> 2) & 7;
    int kk = b & 3;
    int lane = threadIdx.x;
    const float* W = (l == 0) ? W1 : (l == 1) ? W2 : W3;
    int row = nt * 16 + (lane & 15);
    int cb = kk * 32 + (lane >> 4) * 8;
    const float* g = W + row * DIM + cb;
    float4 f0 = *(const float4*)g;
    float4 f1 = *(const float4*)(g + 4);
    uint4 o;
    o.x = pk2(f0.x, f0.y);
    o.y = pk2(f0.z, f0.w);
    o.z = pk2(f1.x, f1.y);
    o.w = pk2(f1.z, f1.w);
    wb4[(size_t)b * 64 + lane] = o;
}

// ---------------- x f32 -> bf16 (padded rows zeroed) ----------------

__global__ __launch_bounds__(256) void xconv_kernel(const float* __restrict__ x,
                                                    unsigned short* __restrict__ xb) {
    int i = blockIdx.x * blockDim.x + threadIdx.x;
    int stride = gridDim.x * blockDim.x;
    const int TOT = N_PAD * DIM / 8;
    for (; i < TOT; i += stride) {
        int row = i >> 4;
        int ks = i & 15;
        uint4 o = {0, 0, 0, 0};
        if (row < N_NODES) {
            const float* g = x + (size_t)row * DIM + ks * 8;
            float4 f0 = *(const float4*)g;
            float4 f1 = *(const float4*)(g + 4);
            o.x = pk2(f0.x, f0.y);
            o.y = pk2(f0.z, f0.w);
            o.z = pk2(f1.x, f1.y);
            o.w = pk2(f1.z, f1.w);
        }
        ((uint4*)xb)[i] = o;
    }
}

// ---------------- fused agg + MFMA GEMM ----------------
// Per block: 64 output rows. Phase 1: 8 groups x 32 lanes gather bf16 rows
// (optionally applying BN+ReLU of the PREVIOUS layer on the fly), accumulate
// f32, pack bf16 into swizzled LDS tile. Phase 2: verified MFMA part:
// y = T @ W^T (bias cancels in BN), fused colsum/colsumsq, y stored bf16.

template <bool BN>
__global__ __launch_bounds__(256) void agg_gemm_kernel(const unsigned short* __restrict__ hin,
                                                       const int* __restrict__ off,
                                                       const int* __restrict__ csr,
                                                       const float* __restrict__ eps_arr, int layer,
                                                       const float* __restrict__ bnsc,
                                                       const float* __restrict__ bnsh,
                                                       const uint4* __restrict__ wb4,
                                                       unsigned short* __restrict__ y,
                                                       float* __restrict__ colsum,
                                                       float* __restrict__ colsumsq) {
    __shared__ unsigned short tile[64 * DIM];  // bf16, 16B-granular XOR swizzle
    __shared__ float sstat[4][DIM];
    __shared__ float sstatq[4][DIM];
    int tid = threadIdx.x;
    int row0 = blockIdx.x * 64;
    int grp = tid >> 5;
    int lane = tid & 31;
    float se = 1.0f + eps_arr[layer];
    float4 sc = {0, 0, 0, 0}, sh = {0, 0, 0, 0};
    if (BN) {
        sc = *(const float4*)(bnsc + lane * 4);
        sh = *(const float4*)(bnsh + lane * 4);
    }

#pragma unroll 1
    for (int r8 = 0; r8 < 8; ++r8) {
        int trow = grp * 8 + r8;
        int row = row0 + trow;
        float a0 = 0.f, a1 = 0.f, a2 = 0.f, a3 = 0.f;
        if (row < N_NODES) {
            const uint2* base = (const uint2*)(hin) + lane;  // lane*8 bytes into a row
            uint2 pv = base[(size_t)row * (DIM / 4)];
            float e0, e1, e2, e3;
            dec4(pv, e0, e1, e2, e3);
            if (BN) {
                e0 = fmaxf(fmaf(e0, sc.x, sh.x), 0.f);
                e1 = fmaxf(fmaf(e1, sc.y, sh.y), 0.f);
                e2 = fmaxf(fmaf(e2, sc.z, sh.z), 0.f);
                e3 = fmaxf(fmaf(e3, sc.w, sh.w), 0.f);
            }
            a0 = se * e0; a1 = se * e1; a2 = se * e2; a3 = se * e3;
            int k = off[row], e = off[row + 1];
            for (; k + 1 < e; k += 2) {
                int s0 = csr[k], s1 = csr[k + 1];
                uint2 p0 = base[(size_t)s0 * (DIM / 4)];
                uint2 p1 = base[(size_t)s1 * (DIM / 4)];
                float f0, f1, f2, f3, g0, g1, g2, g3;
                dec4(p0, f0, f1, f2, f3);
                dec4(p1, g0, g1, g2, g3);
                if (BN) {
                    f0 = fmaxf(fmaf(f0, sc.x, sh.x), 0.f);
                    f1 = fmaxf(fmaf(f1, sc.y, sh.y), 0.f);
                    f2 = fmaxf(fmaf(f2, sc.z, sh.z), 0.f);
                    f3 = fmaxf(fmaf(f3, sc.w, sh.w), 0.f);
                    g0 = fmaxf(fmaf(g0, sc.x, sh.x), 0.f);
                    g1 = fmaxf(fmaf(g1, sc.y, sh.y), 0.f);
                    g2 = fmaxf(fmaf(g2, sc.z, sh.z), 0.f);
                    g3 = fmaxf(fmaf(g3, sc.w, sh.w), 0.f);
                }
                a0 += f0 + g0; a1 += f1 + g1; a2 += f2 + g2; a3 += f3 + g3;
            }
            if (k < e) {
                int s0 = csr[k];
                uint2 p0 = base[(size_t)s0 * (DIM / 4)];
                float f0, f1, f2, f3;
                dec4(p0, f0, f1, f2, f3);
                if (BN) {
                    f0 = fmaxf(fmaf(f0, sc.x, sh.x), 0.f);
                    f1 = fmaxf(fmaf(f1, sc.y, sh.y), 0.f);
                    f2 = fmaxf(fmaf(f2, sc.z, sh.z), 0.f);
                    f3 = fmaxf(fmaf(f3, sc.w, sh.w), 0.f);
                }
                a0 += f0; a1 += f1; a2 += f2; a3 += f3;
            }
        }
        uint2 pw;
        pw.x = pk2(a0, a1);
        pw.y = pk2(a2, a3);
        int byte = (trow * 256 + lane * 8) ^ ((trow & 7) << 4);
        *(uint2*)((char*)tile + byte) = pw;
    }
    __syncthreads();

    // ---- MFMA phase (layout verified R5) ----
    int w = tid >> 6;
    int l = tid & 63;
    int lr = l & 15;
    int lg = l >> 4;
    bf16x8 a[4];
#pragma unroll
    for (int kk = 0; kk < 4; ++kk) {
        int row = w * 16 + lr;
        int byte = (row * 256 + kk * 64 + lg * 16) ^ ((row & 7) << 4);
        a[kk] = __builtin_bit_cast(bf16x8, *(uint4*)((char*)tile + byte));
    }

#pragma unroll
    for (int nt = 0; nt < 8; ++nt) {
        f32x4 acc = {0.0f, 0.0f, 0.0f, 0.0f};
#pragma unroll
        for (int kk = 0; kk < 4; ++kk) {
            bf16x8 b = __builtin_bit_cast(bf16x8, wb4[(nt * 4 + kk) * 64 + l]);
            acc = __builtin_amdgcn_mfma_f32_16x16x32_bf16(a[kk], b, acc, 0, 0, 0);
        }
        int col = nt * 16 + lr;
        size_t base = (size_t)(row0 + w * 16 + lg * 4) * DIM + col;
        y[base] = f2bf(acc[0]);
        y[base + DIM] = f2bf(acc[1]);
        y[base + 2 * DIM] = f2bf(acc[2]);
        y[base + 3 * DIM] = f2bf(acc[3]);
        float s = acc[0] + acc[1] + acc[2] + acc[3];
        float q = acc[0] * acc[0] + acc[1] * acc[1] + acc[2] * acc[2] + acc[3] * acc[3];
        s += __shfl_xor(s, 16);
        s += __shfl_xor(s, 32);
        q += __shfl_xor(q, 16);
        q += __shfl_xor(q, 32);
        if (lg == 0) {
            sstat[w][col] = s;
            sstatq[w][col] = q;
        }
    }
    __syncthreads();
    if (tid < DIM) {
        float s = sstat[0][tid] + sstat[1][tid] + sstat[2][tid] + sstat[3][tid];
        float q = sstatq[0][tid] + sstatq[1][tid] + sstatq[2][tid] + sstatq[3][tid];
        atomicAdd(&colsum[tid], s);
        atomicAdd(&colsumsq[tid], q);
    }
}

// ---------------- BN finalize ----------------

__global__ void bnfin_kernel(float* __restrict__ colsum, float* __restrict__ colsumsq,
                             const float* __restrict__ gamma, const float* __restrict__ beta,
                             float* __restrict__ scale, float* __restrict__ shift) {
    int d = threadIdx.x;
    float m = colsum[d] * (1.0f / N_NODES);
    float v = colsumsq[d] * (1.0f / N_NODES) - m * m;
    float sc = gamma[d] * rsqrtf(v + 1e-5f);
    scale[d] = sc;
    shift[d] = beta[d] - m * sc;
    colsum[d] = 0.0f;
    colsumsq[d] = 0.0f;
}

// ---------------- global mean pool (BN+ReLU of last layer fused) ----------------

__global__ __launch_bounds__(128) void pool_kernel(const unsigned short* __restrict__ y,
                                                   const int* __restrict__ batch,
                                                   const float* __restrict__ bnsc,
                                                   const float* __restrict__ bnsh,
                                                   float* __restrict__ out) {
    int gph = blockIdx.x;
    int d = threadIdx.x;
    int lo = 0, hi = N_NODES;
    while (lo < hi) {
        int mid = (lo + hi) >> 1;
        if (batch[mid] < gph) lo = mid + 1; else hi = mid;
    }
    int start = lo;
    hi = N_NODES;
    while (lo < hi) {
        int mid = (lo + hi) >> 1;
        if (batch[mid] < gph + 1) lo = mid + 1; else hi = mid;
    }
    int end = lo;
    float sc = bnsc[d], sh = bnsh[d];
    float s = 0.0f;
    for (int n = start; n < end; ++n) {
        float v = bf2f(y[(size_t)n * DIM + d]);
        s += fmaxf(fmaf(v, sc, sh), 0.0f);
    }
    out[gph * DIM + d] = s / fmaxf((float)(end - start), 1.0f);
}

// ---------------- launch ----------------

extern "C" void kernel_launch(void* const* d_in, const int* in_sizes, int n_in,
                              void* d_out, int out_size, void* d_ws, size_t ws_size,
                              hipStream_t stream) {
    const float* x = (const float*)d_in[0];
    const int* ei = (const int*)d_in[1];
    const int* batch = (const int*)d_in[2];
    const float* Wp[3] = {(const float*)d_in[3], (const float*)d_in[5], (const float*)d_in[7]};
    const float* eps = (const float*)d_in[9];
    const float* gamma = (const float*)d_in[10];
    const float* beta = (const float*)d_in[11];
    float* out = (float*)d_out;

    char* ws = (char*)d_ws;
    size_t o = 0;
    auto alloc = [&](size_t bytes) {
        void* p = ws + o;
        o = (o + bytes + 255) & ~(size_t)255;
        return p;
    };
    int* deg = (int*)alloc(N_NODES * sizeof(int));
    int* off = (int*)alloc((N_NODES + 1) * sizeof(int));
    int* cursor = (int*)alloc(N_NODES * sizeof(int));
    int* partials = (int*)alloc(SCAN_NB * sizeof(int));
    int* csr = (int*)alloc(N_EDGES * sizeof(int));
    uint4* wb4 = (uint4*)alloc(3 * 8 * 4 * 64 * 16);
    float* colsum = (float*)alloc(DIM * sizeof(float));
    float* colsumsq = (float*)alloc(DIM * sizeof(float));
    float* bnsc = (float*)alloc(DIM * sizeof(float));
    float* bnsh = (float*)alloc(DIM * sizeof(float));
    unsigned short* xb = (unsigned short*)alloc((size_t)N_PAD * DIM * 2);
    unsigned short* y0 = (unsigned short*)alloc((size_t)N_PAD * DIM * 2);
    unsigned short* y1 = (unsigned short*)alloc((size_t)N_PAD * DIM * 2);

    hipMemsetAsync(deg, 0, N_NODES * sizeof(int), stream);
    hipMemsetAsync(colsum, 0, DIM * sizeof(float), stream);
    hipMemsetAsync(colsumsq, 0, DIM * sizeof(float), stream);

    hist_part_kernel<<<1024, 256, 0, stream>>>(ei + N_EDGES, deg);
    scan_partial_kernel<<<SCAN_NB, SCAN_BLOCK, 0, stream>>>(deg, partials);
    scan_partials_kernel<<<1, 512, 0, stream>>>(partials, off);
    scan_scatter_kernel<<<SCAN_NB, SCAN_BLOCK, 0, stream>>>(deg, partials, off, cursor);
    fill_part_kernel<<<1024, 256, 0, stream>>>(ei, ei + N_EDGES, cursor, csr);
    wprep_kernel<<<96, 64, 0, stream>>>(Wp[0], Wp[1], Wp[2], wb4);
    xconv_kernel<<<2048, 256, 0, stream>>>(x, xb);

    const int NBLK = N_PAD / 64;  // 1563
    // layer 0: raw bf16 x input
    agg_gemm_kernel<false><<<NBLK, 256, 0, stream>>>(xb, off, csr, eps, 0, bnsc, bnsh,
                                                     wb4, y0, colsum, colsumsq);
    bnfin_kernel<<<1, DIM, 0, stream>>>(colsum, colsumsq, gamma, beta, bnsc, bnsh);
    // layer 1: BN+ReLU of layer 0 fused into gather
    agg_gemm_kernel<true><<<NBLK, 256, 0, stream>>>(y0, off, csr, eps, 1, bnsc, bnsh,
                                                    wb4 + 2048, y1, colsum, colsumsq);
    bnfin_kernel<<<1, DIM, 0, stream>>>(colsum, colsumsq, gamma + DIM, beta + DIM, bnsc, bnsh);
    // layer 2
    agg_gemm_kernel<true><<<NBLK, 256, 0, stream>>>(y1, off, csr, eps, 2, bnsc, bnsh,
                                                    wb4 + 4096, y0, colsum, colsumsq);
    bnfin_kernel<<<1, DIM, 0, stream>>>(colsum, colsumsq, gamma + 2 * DIM, beta + 2 * DIM, bnsc, bnsh);
    // pool with final BN+ReLU fused
    pool_kernel<<<N_GRAPHS, DIM, 0, stream>>>(y0, batch, bnsc, bnsh, out);
}

// Round 7
// 614.878 us; speedup vs baseline: 2.2381x; 1.0671x over previous
//
#include <hip/hip_runtime.h>

#define N_NODES 100000
#define N_PAD 100032   // 1563 * 64
#define N_EDGES 1600000
#define DIM 128
#define N_GRAPHS 1024

#define SCAN_BLOCK 256
#define SCAN_NB ((N_NODES + SCAN_BLOCK - 1) / SCAN_BLOCK)  // 391

#define NPART 8
#define PART_SZ 12500

typedef __bf16 bf16x8 __attribute__((ext_vector_type(8)));
typedef float f32x4 __attribute__((ext_vector_type(4)));

__device__ __forceinline__ unsigned short f2bf(float f) {
    unsigned u = __builtin_bit_cast(unsigned, f);
    u += 0x7fffu + ((u >> 16) & 1u);  // RNE
    return (unsigned short)(u >> 16);
}
__device__ __forceinline__ unsigned pk2(float a, float b) {
    return (unsigned)f2bf(a) | ((unsigned)f2bf(b) << 16);
}
__device__ __forceinline__ float bf2f(unsigned short s) {
    return __builtin_bit_cast(float, (unsigned)s << 16);
}
// decode 2 bf16 packed in a uint
__device__ __forceinline__ void dec2(unsigned p, float& lo, float& hi) {
    lo = __builtin_bit_cast(float, p << 16);
    hi = __builtin_bit_cast(float, p & 0xffff0000u);
}

// ---------------- CSR build (XCD-partitioned by dst range) ----------------

__global__ __launch_bounds__(256) void hist_part_kernel(const int* __restrict__ dst,
                                                        int* __restrict__ deg) {
    int p = blockIdx.x & (NPART - 1);
    int bgrp = blockIdx.x >> 3;
    int nb = gridDim.x >> 3;
    int tid = bgrp * blockDim.x + threadIdx.x;
    int nthreads = nb * blockDim.x;
    const int NE4 = N_EDGES / 4;
    for (int i = tid; i < NE4; i += nthreads) {
        int4 d4 = ((const int4*)dst)[i];
        if (d4.x / PART_SZ == p) atomicAdd(&deg[d4.x], 1);
        if (d4.y / PART_SZ == p) atomicAdd(&deg[d4.y], 1);
        if (d4.z / PART_SZ == p) atomicAdd(&deg[d4.z], 1);
        if (d4.w / PART_SZ == p) atomicAdd(&deg[d4.w], 1);
    }
}

__global__ __launch_bounds__(256) void fill_part_kernel(const int* __restrict__ src,
                                                        const int* __restrict__ dst,
                                                        int* __restrict__ cursor,
                                                        int* __restrict__ csr) {
    int p = blockIdx.x & (NPART - 1);
    int bgrp = blockIdx.x >> 3;
    int nb = gridDim.x >> 3;
    int tid = bgrp * blockDim.x + threadIdx.x;
    int nthreads = nb * blockDim.x;
    const int NE4 = N_EDGES / 4;
    for (int i = tid; i < NE4; i += nthreads) {
        int4 d4 = ((const int4*)dst)[i];
        int4 s4 = ((const int4*)src)[i];
        if (d4.x / PART_SZ == p) csr[atomicAdd(&cursor[d4.x], 1)] = s4.x;
        if (d4.y / PART_SZ == p) csr[atomicAdd(&cursor[d4.y], 1)] = s4.y;
        if (d4.z / PART_SZ == p) csr[atomicAdd(&cursor[d4.z], 1)] = s4.z;
        if (d4.w / PART_SZ == p) csr[atomicAdd(&cursor[d4.w], 1)] = s4.w;
    }
}

// ---------------- hierarchical scan ----------------

__global__ __launch_bounds__(SCAN_BLOCK) void scan_partial_kernel(const int* __restrict__ deg,
                                                                  int* __restrict__ partials) {
    __shared__ int red[SCAN_BLOCK / 64];
    int i = blockIdx.x * SCAN_BLOCK + threadIdx.x;
    int v = (i < N_NODES) ? deg[i] : 0;
    for (int o = 32; o > 0; o >>= 1) v += __shfl_down(v, o, 64);
    if ((threadIdx.x & 63) == 0) red[threadIdx.x >> 6] = v;
    __syncthreads();
    if (threadIdx.x == 0) {
        int s = 0;
#pragma unroll
        for (int w = 0; w < SCAN_BLOCK / 64; ++w) s += red[w];
        partials[blockIdx.x] = s;
    }
}

__global__ __launch_bounds__(512) void scan_partials_kernel(int* __restrict__ partials,
                                                            int* __restrict__ off) {
    __shared__ int sm[512];
    int t = threadIdx.x;
    int v = (t < SCAN_NB) ? partials[t] : 0;
    sm[t] = v;
    __syncthreads();
    for (int o = 1; o < 512; o <<= 1) {
        int u = (t >= o) ? sm[t - o] : 0;
        __syncthreads();
        sm[t] += u;
        __syncthreads();
    }
    if (t < SCAN_NB) partials[t] = sm[t] - v;
    if (t == 0) off[N_NODES] = sm[511];
}

__global__ __launch_bounds__(SCAN_BLOCK) void scan_scatter_kernel(const int* __restrict__ deg,
                                                                  const int* __restrict__ partials,
                                                                  int* __restrict__ off,
                                                                  int* __restrict__ cursor) {
    __shared__ int sm[SCAN_BLOCK];
    int t = threadIdx.x;
    int i = blockIdx.x * SCAN_BLOCK + t;
    int v = (i < N_NODES) ? deg[i] : 0;
    sm[t] = v;
    __syncthreads();
    for (int o = 1; o < SCAN_BLOCK; o <<= 1) {
        int u = (t >= o) ? sm[t - o] : 0;
        __syncthreads();
        sm[t] += u;
        __syncthreads();
    }
    if (i < N_NODES) {
        int r = partials[blockIdx.x] + sm[t] - v;
        off[i] = r;
        cursor[i] = r;
    }
}

// ---------------- W -> bf16 B-fragment layout (verified R5) ----------------

__global__ __launch_bounds__(64) void wprep_kernel(const float* __restrict__ W1,
                                                   const float* __restrict__ W2,
                                                   const float* __restrict__ W3,
                                                   uint4* __restrict__ wb4) {
    int b = blockIdx.x;           // l*32 + nt*4 + kk
    int l = b >> 5;
    int nt = (b >> 2) & 7;
    int kk = b & 3;
    int lane = threadIdx.x;
    const float* W = (l == 0) ? W1 : (l == 1) ? W2 : W3;
    int row = nt * 16 + (lane & 15);
    int cb = kk * 32 + (lane >> 4) * 8;
    const float* g = W + row * DIM + cb;
    float4 f0 = *(const float4*)g;
    float4 f1 = *(const float4*)(g + 4);
    uint4 o;
    o.x = pk2(f0.x, f0.y);
    o.y = pk2(f0.z, f0.w);
    o.z = pk2(f1.x, f1.y);
    o.w = pk2(f1.z, f1.w);
    wb4[(size_t)b * 64 + lane] = o;
}

// ---------------- x f32 -> bf16 (padded rows zeroed) ----------------

__global__ __launch_bounds__(256) void xconv_kernel(const float* __restrict__ x,
                                                    unsigned short* __restrict__ xb) {
    int i = blockIdx.x * blockDim.x + threadIdx.x;
    int stride = gridDim.x * blockDim.x;
    const int TOT = N_PAD * DIM / 8;
    for (; i < TOT; i += stride) {
        int row = i >> 4;
        int ks = i & 15;
        uint4 o = {0, 0, 0, 0};
        if (row < N_NODES) {
            const float* g = x + (size_t)row * DIM + ks * 8;
            float4 f0 = *(const float4*)g;
            float4 f1 = *(const float4*)(g + 4);
            o.x = pk2(f0.x, f0.y);
            o.y = pk2(f0.z, f0.w);
            o.z = pk2(f1.x, f1.y);
            o.w = pk2(f1.z, f1.w);
        }
        ((uint4*)xb)[i] = o;
    }
}

// ---------------- fused agg + MFMA GEMM ----------------
// Gather: 16 lanes x uint4 (16B/lane) per 256B bf16 row -> 1KB per wave-load,
// 4-edge unroll for 4 in-flight gathers per group (R6 was 8B/lane x 2-unroll:
// latency-bound at 54% occ / 21% HBM). Lane owns 8 dims. MFMA phase verified.

template <bool BN>
__global__ __launch_bounds__(256) void agg_gemm_kernel(const unsigned short* __restrict__ hin,
                                                       const int* __restrict__ off,
                                                       const int* __restrict__ csr,
                                                       const float* __restrict__ eps_arr, int layer,
                                                       const float* __restrict__ bnsc,
                                                       const float* __restrict__ bnsh,
                                                       const uint4* __restrict__ wb4,
                                                       unsigned short* __restrict__ y,
                                                       float* __restrict__ colsum,
                                                       float* __restrict__ colsumsq) {
    __shared__ unsigned short tile[64 * DIM];  // bf16, 16B-granular XOR swizzle
    __shared__ float sstat[4][DIM];
    __shared__ float sstatq[4][DIM];
    int tid = threadIdx.x;
    int row0 = blockIdx.x * 64;
    int grp = tid >> 4;    // 16 groups of 16 lanes
    int lane = tid & 15;   // owns dims lane*8 .. lane*8+7
    float se = 1.0f + eps_arr[layer];
    float sc[8], sh[8];
    if (BN) {
        float4 c0 = *(const float4*)(bnsc + lane * 8);
        float4 c1 = *(const float4*)(bnsc + lane * 8 + 4);
        float4 h0 = *(const float4*)(bnsh + lane * 8);
        float4 h1 = *(const float4*)(bnsh + lane * 8 + 4);
        sc[0] = c0.x; sc[1] = c0.y; sc[2] = c0.z; sc[3] = c0.w;
        sc[4] = c1.x; sc[5] = c1.y; sc[6] = c1.z; sc[7] = c1.w;
        sh[0] = h0.x; sh[1] = h0.y; sh[2] = h0.z; sh[3] = h0.w;
        sh[4] = h1.x; sh[5] = h1.y; sh[6] = h1.z; sh[7] = h1.w;
    }
    const uint4* base = (const uint4*)hin + lane;  // lane*16 bytes into a row

#pragma unroll 1
    for (int r4 = 0; r4 < 4; ++r4) {
        int trow = grp * 4 + r4;
        int row = row0 + trow;
        float a[8] = {0.f, 0.f, 0.f, 0.f, 0.f, 0.f, 0.f, 0.f};
        if (row < N_NODES) {
            // self term
            {
                uint4 pv = base[(size_t)row * (DIM / 8)];
                float v[8];
                dec2(pv.x, v[0], v[1]); dec2(pv.y, v[2], v[3]);
                dec2(pv.z, v[4], v[5]); dec2(pv.w, v[6], v[7]);
#pragma unroll
                for (int j = 0; j < 8; ++j) {
                    if (BN) v[j] = fmaxf(fmaf(v[j], sc[j], sh[j]), 0.f);
                    a[j] = se * v[j];
                }
            }
            int k = off[row], e = off[row + 1];
            for (; k + 3 < e; k += 4) {
                int s0 = csr[k], s1 = csr[k + 1], s2 = csr[k + 2], s3 = csr[k + 3];
                uint4 p0 = base[(size_t)s0 * (DIM / 8)];
                uint4 p1 = base[(size_t)s1 * (DIM / 8)];
                uint4 p2 = base[(size_t)s2 * (DIM / 8)];
                uint4 p3 = base[(size_t)s3 * (DIM / 8)];
                float v0[8], v1[8], v2[8], v3[8];
                dec2(p0.x, v0[0], v0[1]); dec2(p0.y, v0[2], v0[3]);
                dec2(p0.z, v0[4], v0[5]); dec2(p0.w, v0[6], v0[7]);
                dec2(p1.x, v1[0], v1[1]); dec2(p1.y, v1[2], v1[3]);
                dec2(p1.z, v1[4], v1[5]); dec2(p1.w, v1[6], v1[7]);
                dec2(p2.x, v2[0], v2[1]); dec2(p2.y, v2[2], v2[3]);
                dec2(p2.z, v2[4], v2[5]); dec2(p2.w, v2[6], v2[7]);
                dec2(p3.x, v3[0], v3[1]); dec2(p3.y, v3[2], v3[3]);
                dec2(p3.z, v3[4], v3[5]); dec2(p3.w, v3[6], v3[7]);
#pragma unroll
                for (int j = 0; j < 8; ++j) {
                    if (BN) {
                        v0[j] = fmaxf(fmaf(v0[j], sc[j], sh[j]), 0.f);
                        v1[j] = fmaxf(fmaf(v1[j], sc[j], sh[j]), 0.f);
                        v2[j] = fmaxf(fmaf(v2[j], sc[j], sh[j]), 0.f);
                        v3[j] = fmaxf(fmaf(v3[j], sc[j], sh[j]), 0.f);
                    }
                    a[j] += (v0[j] + v1[j]) + (v2[j] + v3[j]);
                }
            }
            for (; k < e; ++k) {
                int s0 = csr[k];
                uint4 p0 = base[(size_t)s0 * (DIM / 8)];
                float v0[8];
                dec2(p0.x, v0[0], v0[1]); dec2(p0.y, v0[2], v0[3]);
                dec2(p0.z, v0[4], v0[5]); dec2(p0.w, v0[6], v0[7]);
#pragma unroll
                for (int j = 0; j < 8; ++j) {
                    if (BN) v0[j] = fmaxf(fmaf(v0[j], sc[j], sh[j]), 0.f);
                    a[j] += v0[j];
                }
            }
        }
        uint4 pw;
        pw.x = pk2(a[0], a[1]);
        pw.y = pk2(a[2], a[3]);
        pw.z = pk2(a[4], a[5]);
        pw.w = pk2(a[6], a[7]);
        int byte = (trow * 256 + lane * 16) ^ ((trow & 7) << 4);
        *(uint4*)((char*)tile + byte) = pw;
    }
    __syncthreads();

    // ---- MFMA phase (layout verified R5) ----
    int w = tid >> 6;
    int l = tid & 63;
    int lr = l & 15;
    int lg = l >> 4;
    bf16x8 a[4];
#pragma unroll
    for (int kk = 0; kk < 4; ++kk) {
        int row = w * 16 + lr;
        int byte = (row * 256 + kk * 64 + lg * 16) ^ ((row & 7) << 4);
        a[kk] = __builtin_bit_cast(bf16x8, *(uint4*)((char*)tile + byte));
    }

#pragma unroll
    for (int nt = 0; nt < 8; ++nt) {
        f32x4 acc = {0.0f, 0.0f, 0.0f, 0.0f};
#pragma unroll
        for (int kk = 0; kk < 4; ++kk) {
            bf16x8 b = __builtin_bit_cast(bf16x8, wb4[(nt * 4 + kk) * 64 + l]);
            acc = __builtin_amdgcn_mfma_f32_16x16x32_bf16(a[kk], b, acc, 0, 0, 0);
        }
        int col = nt * 16 + lr;
        size_t base2 = (size_t)(row0 + w * 16 + lg * 4) * DIM + col;
        y[base2] = f2bf(acc[0]);
        y[base2 + DIM] = f2bf(acc[1]);
        y[base2 + 2 * DIM] = f2bf(acc[2]);
        y[base2 + 3 * DIM] = f2bf(acc[3]);
        float s = acc[0] + acc[1] + acc[2] + acc[3];
        float q = acc[0] * acc[0] + acc[1] * acc[1] + acc[2] * acc[2] + acc[3] * acc[3];
        s += __shfl_xor(s, 16);
        s += __shfl_xor(s, 32);
        q += __shfl_xor(q, 16);
        q += __shfl_xor(q, 32);
        if (lg == 0) {
            sstat[w][col] = s;
            sstatq[w][col] = q;
        }
    }
    __syncthreads();
    if (tid < DIM) {
        float s = sstat[0][tid] + sstat[1][tid] + sstat[2][tid] + sstat[3][tid];
        float q = sstatq[0][tid] + sstatq[1][tid] + sstatq[2][tid] + sstatq[3][tid];
        atomicAdd(&colsum[tid], s);
        atomicAdd(&colsumsq[tid], q);
    }
}

// ---------------- BN finalize ----------------

__global__ void bnfin_kernel(float* __restrict__ colsum, float* __restrict__ colsumsq,
                             const float* __restrict__ gamma, const float* __restrict__ beta,
                             float* __restrict__ scale, float* __restrict__ shift) {
    int d = threadIdx.x;
    float m = colsum[d] * (1.0f / N_NODES);
    float v = colsumsq[d] * (1.0f / N_NODES) - m * m;
    float sc = gamma[d] * rsqrtf(v + 1e-5f);
    scale[d] = sc;
    shift[d] = beta[d] - m * sc;
    colsum[d] = 0.0f;
    colsumsq[d] = 0.0f;
}

// ---------------- global mean pool (BN+ReLU of last layer fused) ----------------

__global__ __launch_bounds__(128) void pool_kernel(const unsigned short* __restrict__ y,
                                                   const int* __restrict__ batch,
                                                   const float* __restrict__ bnsc,
                                                   const float* __restrict__ bnsh,
                                                   float* __restrict__ out) {
    int gph = blockIdx.x;
    int d = threadIdx.x;
    int lo = 0, hi = N_NODES;
    while (lo < hi) {
        int mid = (lo + hi) >> 1;
        if (batch[mid] < gph) lo = mid + 1; else hi = mid;
    }
    int start = lo;
    hi = N_NODES;
    while (lo < hi) {
        int mid = (lo + hi) >> 1;
        if (batch[mid] < gph + 1) lo = mid + 1; else hi = mid;
    }
    int end = lo;
    float sc = bnsc[d], sh = bnsh[d];
    float s = 0.0f;
    for (int n = start; n < end; ++n) {
        float v = bf2f(y[(size_t)n * DIM + d]);
        s += fmaxf(fmaf(v, sc, sh), 0.0f);
    }
    out[gph * DIM + d] = s / fmaxf((float)(end - start), 1.0f);
}

// ---------------- launch ----------------

extern "C" void kernel_launch(void* const* d_in, const int* in_sizes, int n_in,
                              void* d_out, int out_size, void* d_ws, size_t ws_size,
                              hipStream_t stream) {
    const float* x = (const float*)d_in[0];
    const int* ei = (const int*)d_in[1];
    const int* batch = (const int*)d_in[2];
    const float* Wp[3] = {(const float*)d_in[3], (const float*)d_in[5], (const float*)d_in[7]};
    const float* eps = (const float*)d_in[9];
    const float* gamma = (const float*)d_in[10];
    const float* beta = (const float*)d_in[11];
    float* out = (float*)d_out;

    char* ws = (char*)d_ws;
    size_t o = 0;
    auto alloc = [&](size_t bytes) {
        void* p = ws + o;
        o = (o + bytes + 255) & ~(size_t)255;
        return p;
    };
    int* deg = (int*)alloc(N_NODES * sizeof(int));
    int* off = (int*)alloc((N_NODES + 1) * sizeof(int));
    int* cursor = (int*)alloc(N_NODES * sizeof(int));
    int* partials = (int*)alloc(SCAN_NB * sizeof(int));
    int* csr = (int*)alloc(N_EDGES * sizeof(int));
    uint4* wb4 = (uint4*)alloc(3 * 8 * 4 * 64 * 16);
    float* colsum = (float*)alloc(DIM * sizeof(float));
    float* colsumsq = (float*)alloc(DIM * sizeof(float));
    float* bnsc = (float*)alloc(DIM * sizeof(float));
    float* bnsh = (float*)alloc(DIM * sizeof(float));
    unsigned short* xb = (unsigned short*)alloc((size_t)N_PAD * DIM * 2);
    unsigned short* y0 = (unsigned short*)alloc((size_t)N_PAD * DIM * 2);
    unsigned short* y1 = (unsigned short*)alloc((size_t)N_PAD * DIM * 2);

    hipMemsetAsync(deg, 0, N_NODES * sizeof(int), stream);
    hipMemsetAsync(colsum, 0, DIM * sizeof(float), stream);
    hipMemsetAsync(colsumsq, 0, DIM * sizeof(float), stream);

    hist_part_kernel<<<1024, 256, 0, stream>>>(ei + N_EDGES, deg);
    scan_partial_kernel<<<SCAN_NB, SCAN_BLOCK, 0, stream>>>(deg, partials);
    scan_partials_kernel<<<1, 512, 0, stream>>>(partials, off);
    scan_scatter_kernel<<<SCAN_NB, SCAN_BLOCK, 0, stream>>>(deg, partials, off, cursor);
    fill_part_kernel<<<1024, 256, 0, stream>>>(ei, ei + N_EDGES, cursor, csr);
    wprep_kernel<<<96, 64, 0, stream>>>(Wp[0], Wp[1], Wp[2], wb4);
    xconv_kernel<<<2048, 256, 0, stream>>>(x, xb);

    const int NBLK = N_PAD / 64;  // 1563
    agg_gemm_kernel<false><<<NBLK, 256, 0, stream>>>(xb, off, csr, eps, 0, bnsc, bnsh,
                                                     wb4, y0, colsum, colsumsq);
    bnfin_kernel<<<1, DIM, 0, stream>>>(colsum, colsumsq, gamma, beta, bnsc, bnsh);
    agg_gemm_kernel<true><<<NBLK, 256, 0, stream>>>(y0, off, csr, eps, 1, bnsc, bnsh,
                                                    wb4 + 2048, y1, colsum, colsumsq);
    bnfin_kernel<<<1, DIM, 0, stream>>>(colsum, colsumsq, gamma + DIM, beta + DIM, bnsc, bnsh);
    agg_gemm_kernel<true><<<NBLK, 256, 0, stream>>>(y1, off, csr, eps, 2, bnsc, bnsh,
                                                    wb4 + 4096, y0, colsum, colsumsq);
    bnfin_kernel<<<1, DIM, 0, stream>>>(colsum, colsumsq, gamma + 2 * DIM, beta + 2 * DIM, bnsc, bnsh);
    pool_kernel<<<N_GRAPHS, DIM, 0, stream>>>(y0, batch, bnsc, bnsh, out);
}

// Round 8
// 594.434 us; speedup vs baseline: 2.3151x; 1.0344x over previous
//
#include <hip/hip_runtime.h>

#define N_NODES 100000
#define N_PAD 100032   // 1563 * 64
#define N_EDGES 1600000
#define DIM 128
#define N_GRAPHS 1024

#define SCAN_BLOCK 256
#define SCAN_NB ((N_NODES + SCAN_BLOCK - 1) / SCAN_BLOCK)  // 391

#define NPART 8
#define PART_SZ 12500

typedef __bf16 bf16x8 __attribute__((ext_vector_type(8)));
typedef float f32x4 __attribute__((ext_vector_type(4)));

__device__ __forceinline__ unsigned short f2bf(float f) {
    unsigned u = __builtin_bit_cast(unsigned, f);
    u += 0x7fffu + ((u >> 16) & 1u);  // RNE
    return (unsigned short)(u >> 16);
}
__device__ __forceinline__ unsigned pk2(float a, float b) {
    return (unsigned)f2bf(a) | ((unsigned)f2bf(b) << 16);
}
__device__ __forceinline__ float bf2f(unsigned short s) {
    return __builtin_bit_cast(float, (unsigned)s << 16);
}
__device__ __forceinline__ void dec2(unsigned p, float& lo, float& hi) {
    lo = __builtin_bit_cast(float, p << 16);
    hi = __builtin_bit_cast(float, p & 0xffff0000u);
}

// decode 16B (8 bf16) and accumulate, optional BN+ReLU of previous layer
template <bool BN>
__device__ __forceinline__ void acc8(uint4 p, float* a, const float* sc, const float* sh) {
    float v[8];
    dec2(p.x, v[0], v[1]);
    dec2(p.y, v[2], v[3]);
    dec2(p.z, v[4], v[5]);
    dec2(p.w, v[6], v[7]);
#pragma unroll
    for (int j = 0; j < 8; ++j) {
        float t = BN ? fmaxf(fmaf(v[j], sc[j], sh[j]), 0.f) : v[j];
        a[j] += t;
    }
}

// ---------------- CSR build (XCD-partitioned by dst range) ----------------

__global__ __launch_bounds__(256) void hist_part_kernel(const int* __restrict__ dst,
                                                        int* __restrict__ deg) {
    int p = blockIdx.x & (NPART - 1);
    int bgrp = blockIdx.x >> 3;
    int nb = gridDim.x >> 3;
    int tid = bgrp * blockDim.x + threadIdx.x;
    int nthreads = nb * blockDim.x;
    const int NE8 = N_EDGES / 8;
    for (int i = tid; i < NE8; i += nthreads) {
        int4 a = ((const int4*)dst)[2 * i];
        int4 b = ((const int4*)dst)[2 * i + 1];
        if (a.x / PART_SZ == p) atomicAdd(&deg[a.x], 1);
        if (a.y / PART_SZ == p) atomicAdd(&deg[a.y], 1);
        if (a.z / PART_SZ == p) atomicAdd(&deg[a.z], 1);
        if (a.w / PART_SZ == p) atomicAdd(&deg[a.w], 1);
        if (b.x / PART_SZ == p) atomicAdd(&deg[b.x], 1);
        if (b.y / PART_SZ == p) atomicAdd(&deg[b.y], 1);
        if (b.z / PART_SZ == p) atomicAdd(&deg[b.z], 1);
        if (b.w / PART_SZ == p) atomicAdd(&deg[b.w], 1);
    }
}

__global__ __launch_bounds__(256) void fill_part_kernel(const int* __restrict__ src,
                                                        const int* __restrict__ dst,
                                                        int* __restrict__ cursor,
                                                        int* __restrict__ csr) {
    int p = blockIdx.x & (NPART - 1);
    int bgrp = blockIdx.x >> 3;
    int nb = gridDim.x >> 3;
    int tid = bgrp * blockDim.x + threadIdx.x;
    int nthreads = nb * blockDim.x;
    const int NE8 = N_EDGES / 8;
    for (int i = tid; i < NE8; i += nthreads) {
        int4 da = ((const int4*)dst)[2 * i];
        int4 db = ((const int4*)dst)[2 * i + 1];
        int4 sa = ((const int4*)src)[2 * i];
        int4 sb = ((const int4*)src)[2 * i + 1];
        if (da.x / PART_SZ == p) csr[atomicAdd(&cursor[da.x], 1)] = sa.x;
        if (da.y / PART_SZ == p) csr[atomicAdd(&cursor[da.y], 1)] = sa.y;
        if (da.z / PART_SZ == p) csr[atomicAdd(&cursor[da.z], 1)] = sa.z;
        if (da.w / PART_SZ == p) csr[atomicAdd(&cursor[da.w], 1)] = sa.w;
        if (db.x / PART_SZ == p) csr[atomicAdd(&cursor[db.x], 1)] = sb.x;
        if (db.y / PART_SZ == p) csr[atomicAdd(&cursor[db.y], 1)] = sb.y;
        if (db.z / PART_SZ == p) csr[atomicAdd(&cursor[db.z], 1)] = sb.z;
        if (db.w / PART_SZ == p) csr[atomicAdd(&cursor[db.w], 1)] = sb.w;
    }
}

// ---------------- hierarchical scan ----------------

__global__ __launch_bounds__(SCAN_BLOCK) void scan_partial_kernel(const int* __restrict__ deg,
                                                                  int* __restrict__ partials) {
    __shared__ int red[SCAN_BLOCK / 64];
    int i = blockIdx.x * SCAN_BLOCK + threadIdx.x;
    int v = (i < N_NODES) ? deg[i] : 0;
    for (int o = 32; o > 0; o >>= 1) v += __shfl_down(v, o, 64);
    if ((threadIdx.x & 63) == 0) red[threadIdx.x >> 6] = v;
    __syncthreads();
    if (threadIdx.x == 0) {
        int s = 0;
#pragma unroll
        for (int w = 0; w < SCAN_BLOCK / 64; ++w) s += red[w];
        partials[blockIdx.x] = s;
    }
}

__global__ __launch_bounds__(512) void scan_partials_kernel(int* __restrict__ partials,
                                                            int* __restrict__ off) {
    __shared__ int sm[512];
    int t = threadIdx.x;
    int v = (t < SCAN_NB) ? partials[t] : 0;
    sm[t] = v;
    __syncthreads();
    for (int o = 1; o < 512; o <<= 1) {
        int u = (t >= o) ? sm[t - o] : 0;
        __syncthreads();
        sm[t] += u;
        __syncthreads();
    }
    if (t < SCAN_NB) partials[t] = sm[t] - v;
    if (t == 0) off[N_NODES] = sm[511];
}

__global__ __launch_bounds__(SCAN_BLOCK) void scan_scatter_kernel(const int* __restrict__ deg,
                                                                  const int* __restrict__ partials,
                                                                  int* __restrict__ off,
                                                                  int* __restrict__ cursor) {
    __shared__ int sm[SCAN_BLOCK];
    int t = threadIdx.x;
    int i = blockIdx.x * SCAN_BLOCK + t;
    int v = (i < N_NODES) ? deg[i] : 0;
    sm[t] = v;
    __syncthreads();
    for (int o = 1; o < SCAN_BLOCK; o <<= 1) {
        int u = (t >= o) ? sm[t - o] : 0;
        __syncthreads();
        sm[t] += u;
        __syncthreads();
    }
    if (i < N_NODES) {
        int r = partials[blockIdx.x] + sm[t] - v;
        off[i] = r;
        cursor[i] = r;
    }
}

// ---------------- W -> bf16 B-fragment layout (verified R5) ----------------

__global__ __launch_bounds__(64) void wprep_kernel(const float* __restrict__ W1,
                                                   const float* __restrict__ W2,
                                                   const float* __restrict__ W3,
                                                   uint4* __restrict__ wb4) {
    int b = blockIdx.x;           // l*32 + nt*4 + kk
    int l = b >> 5;
    int nt = (b >> 2) & 7;
    int kk = b & 3;
    int lane = threadIdx.x;
    const float* W = (l == 0) ? W1 : (l == 1) ? W2 : W3;
    int row = nt * 16 + (lane & 15);
    int cb = kk * 32 + (lane >> 4) * 8;
    const float* g = W + row * DIM + cb;
    float4 f0 = *(const float4*)g;
    float4 f1 = *(const float4*)(g + 4);
    uint4 o;
    o.x = pk2(f0.x, f0.y);
    o.y = pk2(f0.z, f0.w);
    o.z = pk2(f1.x, f1.y);
    o.w = pk2(f1.z, f1.w);
    wb4[(size_t)b * 64 + lane] = o;
}

// ---------------- x f32 -> bf16 (padded rows zeroed) ----------------

__global__ __launch_bounds__(256) void xconv_kernel(const float* __restrict__ x,
                                                    unsigned short* __restrict__ xb) {
    int i = blockIdx.x * blockDim.x + threadIdx.x;
    int stride = gridDim.x * blockDim.x;
    const int TOT = N_PAD * DIM / 8;
    for (; i < TOT; i += stride) {
        int row = i >> 4;
        int ks = i & 15;
        uint4 o = {0, 0, 0, 0};
        if (row < N_NODES) {
            const float* g = x + (size_t)row * DIM + ks * 8;
            float4 f0 = *(const float4*)g;
            float4 f1 = *(const float4*)(g + 4);
            o.x = pk2(f0.x, f0.y);
            o.y = pk2(f0.z, f0.w);
            o.z = pk2(f1.x, f1.y);
            o.w = pk2(f1.z, f1.w);
        }
        ((uint4*)xb)[i] = o;
    }
}

// ---------------- fused agg + MFMA GEMM ----------------
// Gather: 16 lanes x uint4 per 256B bf16 row, 8-edge unroll (8 outstanding
// 1KB wave-loads; R7's 4-deep was latency-bound at 105us, VALU 34%, HBM 27%).
// BN+ReLU of PREVIOUS layer computed inline from per-layer stats (bnfin
// kernels deleted). MFMA phase verified R5.

template <bool BN>
__global__ __launch_bounds__(256) void agg_gemm_kernel(const unsigned short* __restrict__ hin,
                                                       const int* __restrict__ off,
                                                       const int* __restrict__ csr,
                                                       const float* __restrict__ eps_arr, int layer,
                                                       const float* __restrict__ csum_prev,
                                                       const float* __restrict__ csq_prev,
                                                       const float* __restrict__ gamma_prev,
                                                       const float* __restrict__ beta_prev,
                                                       const uint4* __restrict__ wb4,
                                                       unsigned short* __restrict__ y,
                                                       float* __restrict__ csum_out,
                                                       float* __restrict__ csq_out) {
    __shared__ unsigned short tile[64 * DIM];  // bf16, 16B-granular XOR swizzle
    __shared__ float sstat[4][DIM];
    __shared__ float sstatq[4][DIM];
    int tid = threadIdx.x;
    int row0 = blockIdx.x * 64;
    int grp = tid >> 4;    // 16 groups of 16 lanes
    int lane = tid & 15;   // owns dims lane*8 .. lane*8+7
    float se = 1.0f + eps_arr[layer];
    float sc[8], sh[8];
    if (BN) {
#pragma unroll
        for (int j = 0; j < 8; ++j) {
            int d = lane * 8 + j;
            float m = csum_prev[d] * (1.0f / N_NODES);
            float var = csq_prev[d] * (1.0f / N_NODES) - m * m;
            float s = gamma_prev[d] * rsqrtf(var + 1e-5f);
            sc[j] = s;
            sh[j] = beta_prev[d] - m * s;
        }
    }
    const uint4* base = (const uint4*)hin + lane;
    const size_t RS = DIM / 8;  // uint4 per row

#pragma unroll 1
    for (int r4 = 0; r4 < 4; ++r4) {
        int trow = grp * 4 + r4;
        int row = row0 + trow;
        float a[8] = {0.f, 0.f, 0.f, 0.f, 0.f, 0.f, 0.f, 0.f};
        if (row < N_NODES) {
            {   // self term: (1+eps) * h[row]
                uint4 pv = base[(size_t)row * RS];
                float v[8];
                dec2(pv.x, v[0], v[1]); dec2(pv.y, v[2], v[3]);
                dec2(pv.z, v[4], v[5]); dec2(pv.w, v[6], v[7]);
#pragma unroll
                for (int j = 0; j < 8; ++j) {
                    float t = BN ? fmaxf(fmaf(v[j], sc[j], sh[j]), 0.f) : v[j];
                    a[j] = se * t;
                }
            }
            int k = off[row], e = off[row + 1];
            for (; k + 7 < e; k += 8) {
                int s0 = csr[k], s1 = csr[k + 1], s2 = csr[k + 2], s3 = csr[k + 3];
                int s4 = csr[k + 4], s5 = csr[k + 5], s6 = csr[k + 6], s7 = csr[k + 7];
                uint4 p0 = base[(size_t)s0 * RS];
                uint4 p1 = base[(size_t)s1 * RS];
                uint4 p2 = base[(size_t)s2 * RS];
                uint4 p3 = base[(size_t)s3 * RS];
                uint4 p4 = base[(size_t)s4 * RS];
                uint4 p5 = base[(size_t)s5 * RS];
                uint4 p6 = base[(size_t)s6 * RS];
                uint4 p7 = base[(size_t)s7 * RS];
                acc8<BN>(p0, a, sc, sh);
                acc8<BN>(p1, a, sc, sh);
                acc8<BN>(p2, a, sc, sh);
                acc8<BN>(p3, a, sc, sh);
                acc8<BN>(p4, a, sc, sh);
                acc8<BN>(p5, a, sc, sh);
                acc8<BN>(p6, a, sc, sh);
                acc8<BN>(p7, a, sc, sh);
            }
            if (k + 3 < e) {
                int s0 = csr[k], s1 = csr[k + 1], s2 = csr[k + 2], s3 = csr[k + 3];
                uint4 p0 = base[(size_t)s0 * RS];
                uint4 p1 = base[(size_t)s1 * RS];
                uint4 p2 = base[(size_t)s2 * RS];
                uint4 p3 = base[(size_t)s3 * RS];
                acc8<BN>(p0, a, sc, sh);
                acc8<BN>(p1, a, sc, sh);
                acc8<BN>(p2, a, sc, sh);
                acc8<BN>(p3, a, sc, sh);
                k += 4;
            }
            for (; k < e; ++k) {
                uint4 p0 = base[(size_t)csr[k] * RS];
                acc8<BN>(p0, a, sc, sh);
            }
        }
        uint4 pw;
        pw.x = pk2(a[0], a[1]);
        pw.y = pk2(a[2], a[3]);
        pw.z = pk2(a[4], a[5]);
        pw.w = pk2(a[6], a[7]);
        int byte = (trow * 256 + lane * 16) ^ ((trow & 7) << 4);
        *(uint4*)((char*)tile + byte) = pw;
    }
    __syncthreads();

    // ---- MFMA phase (layout verified R5) ----
    int w = tid >> 6;
    int l = tid & 63;
    int lr = l & 15;
    int lg = l >> 4;
    bf16x8 a[4];
#pragma unroll
    for (int kk = 0; kk < 4; ++kk) {
        int row = w * 16 + lr;
        int byte = (row * 256 + kk * 64 + lg * 16) ^ ((row & 7) << 4);
        a[kk] = __builtin_bit_cast(bf16x8, *(uint4*)((char*)tile + byte));
    }

#pragma unroll
    for (int nt = 0; nt < 8; ++nt) {
        f32x4 acc = {0.0f, 0.0f, 0.0f, 0.0f};
#pragma unroll
        for (int kk = 0; kk < 4; ++kk) {
            bf16x8 b = __builtin_bit_cast(bf16x8, wb4[(nt * 4 + kk) * 64 + l]);
            acc = __builtin_amdgcn_mfma_f32_16x16x32_bf16(a[kk], b, acc, 0, 0, 0);
        }
        int col = nt * 16 + lr;
        size_t base2 = (size_t)(row0 + w * 16 + lg * 4) * DIM + col;
        y[base2] = f2bf(acc[0]);
        y[base2 + DIM] = f2bf(acc[1]);
        y[base2 + 2 * DIM] = f2bf(acc[2]);
        y[base2 + 3 * DIM] = f2bf(acc[3]);
        float s = acc[0] + acc[1] + acc[2] + acc[3];
        float q = acc[0] * acc[0] + acc[1] * acc[1] + acc[2] * acc[2] + acc[3] * acc[3];
        s += __shfl_xor(s, 16);
        s += __shfl_xor(s, 32);
        q += __shfl_xor(q, 16);
        q += __shfl_xor(q, 32);
        if (lg == 0) {
            sstat[w][col] = s;
            sstatq[w][col] = q;
        }
    }
    __syncthreads();
    if (tid < DIM) {
        float s = sstat[0][tid] + sstat[1][tid] + sstat[2][tid] + sstat[3][tid];
        float q = sstatq[0][tid] + sstatq[1][tid] + sstatq[2][tid] + sstatq[3][tid];
        atomicAdd(&csum_out[tid], s);
        atomicAdd(&csq_out[tid], q);
    }
}

// ---------------- global mean pool (final BN+ReLU inline, 4-node MLP) -------

__global__ __launch_bounds__(128) void pool_kernel(const unsigned short* __restrict__ y,
                                                   const int* __restrict__ batch,
                                                   const float* __restrict__ csum,
                                                   const float* __restrict__ csq,
                                                   const float* __restrict__ gamma,
                                                   const float* __restrict__ beta,
                                                   float* __restrict__ out) {
    int gph = blockIdx.x;
    int d = threadIdx.x;
    float m = csum[d] * (1.0f / N_NODES);
    float var = csq[d] * (1.0f / N_NODES) - m * m;
    float sc = gamma[d] * rsqrtf(var + 1e-5f);
    float sh = beta[d] - m * sc;
    int lo = 0, hi = N_NODES;
    while (lo < hi) {
        int mid = (lo + hi) >> 1;
        if (batch[mid] < gph) lo = mid + 1; else hi = mid;
    }
    int start = lo;
    hi = N_NODES;
    while (lo < hi) {
        int mid = (lo + hi) >> 1;
        if (batch[mid] < gph + 1) lo = mid + 1; else hi = mid;
    }
    int end = lo;
    float s0 = 0.f, s1 = 0.f, s2 = 0.f, s3 = 0.f;
    int n = start;
    for (; n + 3 < end; n += 4) {
        float v0 = bf2f(y[(size_t)n * DIM + d]);
        float v1 = bf2f(y[(size_t)(n + 1) * DIM + d]);
        float v2 = bf2f(y[(size_t)(n + 2) * DIM + d]);
        float v3 = bf2f(y[(size_t)(n + 3) * DIM + d]);
        s0 += fmaxf(fmaf(v0, sc, sh), 0.0f);
        s1 += fmaxf(fmaf(v1, sc, sh), 0.0f);
        s2 += fmaxf(fmaf(v2, sc, sh), 0.0f);
        s3 += fmaxf(fmaf(v3, sc, sh), 0.0f);
    }
    for (; n < end; ++n) {
        float v = bf2f(y[(size_t)n * DIM + d]);
        s0 += fmaxf(fmaf(v, sc, sh), 0.0f);
    }
    float s = (s0 + s1) + (s2 + s3);
    out[gph * DIM + d] = s / fmaxf((float)(end - start), 1.0f);
}

// ---------------- launch ----------------

extern "C" void kernel_launch(void* const* d_in, const int* in_sizes, int n_in,
                              void* d_out, int out_size, void* d_ws, size_t ws_size,
                              hipStream_t stream) {
    const float* x = (const float*)d_in[0];
    const int* ei = (const int*)d_in[1];
    const int* batch = (const int*)d_in[2];
    const float* Wp[3] = {(const float*)d_in[3], (const float*)d_in[5], (const float*)d_in[7]};
    const float* eps = (const float*)d_in[9];
    const float* gamma = (const float*)d_in[10];
    const float* beta = (const float*)d_in[11];
    float* out = (float*)d_out;

    char* ws = (char*)d_ws;
    size_t o = 0;
    auto alloc = [&](size_t bytes) {
        void* p = ws + o;
        o = (o + bytes + 255) & ~(size_t)255;
        return p;
    };
    int* deg = (int*)alloc(N_NODES * sizeof(int));
    int* off = (int*)alloc((N_NODES + 1) * sizeof(int));
    int* cursor = (int*)alloc(N_NODES * sizeof(int));
    int* partials = (int*)alloc(SCAN_NB * sizeof(int));
    int* csr = (int*)alloc(N_EDGES * sizeof(int));
    uint4* wb4 = (uint4*)alloc(3 * 8 * 4 * 64 * 16);
    float* csums = (float*)alloc(3 * DIM * sizeof(float));   // per-layer colsum
    float* csqs = (float*)alloc(3 * DIM * sizeof(float));    // per-layer colsumsq
    unsigned short* xb = (unsigned short*)alloc((size_t)N_PAD * DIM * 2);
    unsigned short* y0 = (unsigned short*)alloc((size_t)N_PAD * DIM * 2);
    unsigned short* y1 = (unsigned short*)alloc((size_t)N_PAD * DIM * 2);

    hipMemsetAsync(deg, 0, N_NODES * sizeof(int), stream);
    hipMemsetAsync(csums, 0, 3 * DIM * sizeof(float), stream);
    hipMemsetAsync(csqs, 0, 3 * DIM * sizeof(float), stream);

    hist_part_kernel<<<2048, 256, 0, stream>>>(ei + N_EDGES, deg);
    scan_partial_kernel<<<SCAN_NB, SCAN_BLOCK, 0, stream>>>(deg, partials);
    scan_partials_kernel<<<1, 512, 0, stream>>>(partials, off);
    scan_scatter_kernel<<<SCAN_NB, SCAN_BLOCK, 0, stream>>>(deg, partials, off, cursor);
    fill_part_kernel<<<2048, 256, 0, stream>>>(ei, ei + N_EDGES, cursor, csr);
    wprep_kernel<<<96, 64, 0, stream>>>(Wp[0], Wp[1], Wp[2], wb4);
    xconv_kernel<<<2048, 256, 0, stream>>>(x, xb);

    const int NBLK = N_PAD / 64;  // 1563
    agg_gemm_kernel<false><<<NBLK, 256, 0, stream>>>(xb, off, csr, eps, 0,
                                                     nullptr, nullptr, nullptr, nullptr,
                                                     wb4, y0, csums, csqs);
    agg_gemm_kernel<true><<<NBLK, 256, 0, stream>>>(y0, off, csr, eps, 1,
                                                    csums, csqs, gamma, beta,
                                                    wb4 + 2048, y1, csums + DIM, csqs + DIM);
    agg_gemm_kernel<true><<<NBLK, 256, 0, stream>>>(y1, off, csr, eps, 2,
                                                    csums + DIM, csqs + DIM, gamma + DIM, beta + DIM,
                                                    wb4 + 4096, y0, csums + 2 * DIM, csqs + 2 * DIM);
    pool_kernel<<<N_GRAPHS, DIM, 0, stream>>>(y0, batch, csums + 2 * DIM, csqs + 2 * DIM,
                                              gamma + 2 * DIM, beta + 2 * DIM, out);
}

// Round 9
// 581.545 us; speedup vs baseline: 2.3664x; 1.0222x over previous
//
#include <hip/hip_runtime.h>

#define N_NODES 100000
#define N_PAD 100032   // 1563 * 64
#define N_EDGES 1600000
#define DIM 128
#define N_GRAPHS 1024

#define SCAN_BLOCK 256
#define SCAN_NB ((N_NODES + SCAN_BLOCK - 1) / SCAN_BLOCK)  // 391

#define NPART 8
#define PART_SZ 12500

typedef __bf16 bf16x8 __attribute__((ext_vector_type(8)));
typedef float f32x4 __attribute__((ext_vector_type(4)));

__device__ __forceinline__ unsigned short f2bf(float f) {
    unsigned u = __builtin_bit_cast(unsigned, f);
    u += 0x7fffu + ((u >> 16) & 1u);  // RNE
    return (unsigned short)(u >> 16);
}
__device__ __forceinline__ unsigned pk2(float a, float b) {
    return (unsigned)f2bf(a) | ((unsigned)f2bf(b) << 16);
}
__device__ __forceinline__ float bf2f(unsigned short s) {
    return __builtin_bit_cast(float, (unsigned)s << 16);
}
__device__ __forceinline__ void dec2(unsigned p, float& lo, float& hi) {
    lo = __builtin_bit_cast(float, p << 16);
    hi = __builtin_bit_cast(float, p & 0xffff0000u);
}

// decode 16B (8 bf16) and accumulate, optional BN+ReLU of previous layer
template <bool BN>
__device__ __forceinline__ void acc8(uint4 p, float* a, const float* sc, const float* sh) {
    float v[8];
    dec2(p.x, v[0], v[1]);
    dec2(p.y, v[2], v[3]);
    dec2(p.z, v[4], v[5]);
    dec2(p.w, v[6], v[7]);
#pragma unroll
    for (int j = 0; j < 8; ++j) {
        float t = BN ? fmaxf(fmaf(v[j], sc[j], sh[j]), 0.f) : v[j];
        a[j] += t;
    }
}

// ---------------- CSR build ----------------
// hist: plain single-pass (atomics don't write-amplify; only scattered STORES
// in fill do -> fill keeps the XCD partition).

__global__ __launch_bounds__(256) void hist_kernel(const int* __restrict__ dst,
                                                   int* __restrict__ deg) {
    int i = blockIdx.x * blockDim.x + threadIdx.x;
    int stride = gridDim.x * blockDim.x;
    const int NE4 = N_EDGES / 4;
    for (; i < NE4; i += stride) {
        int4 d4 = ((const int4*)dst)[i];
        atomicAdd(&deg[d4.x], 1);
        atomicAdd(&deg[d4.y], 1);
        atomicAdd(&deg[d4.z], 1);
        atomicAdd(&deg[d4.w], 1);
    }
}

__global__ __launch_bounds__(256) void fill_part_kernel(const int* __restrict__ src,
                                                        const int* __restrict__ dst,
                                                        int* __restrict__ cursor,
                                                        int* __restrict__ csr) {
    int p = blockIdx.x & (NPART - 1);
    int bgrp = blockIdx.x >> 3;
    int nb = gridDim.x >> 3;
    int tid = bgrp * blockDim.x + threadIdx.x;
    int nthreads = nb * blockDim.x;
    const int NE8 = N_EDGES / 8;
    for (int i = tid; i < NE8; i += nthreads) {
        int4 da = ((const int4*)dst)[2 * i];
        int4 db = ((const int4*)dst)[2 * i + 1];
        int4 sa = ((const int4*)src)[2 * i];
        int4 sb = ((const int4*)src)[2 * i + 1];
        if (da.x / PART_SZ == p) csr[atomicAdd(&cursor[da.x], 1)] = sa.x;
        if (da.y / PART_SZ == p) csr[atomicAdd(&cursor[da.y], 1)] = sa.y;
        if (da.z / PART_SZ == p) csr[atomicAdd(&cursor[da.z], 1)] = sa.z;
        if (da.w / PART_SZ == p) csr[atomicAdd(&cursor[da.w], 1)] = sa.w;
        if (db.x / PART_SZ == p) csr[atomicAdd(&cursor[db.x], 1)] = sb.x;
        if (db.y / PART_SZ == p) csr[atomicAdd(&cursor[db.y], 1)] = sb.y;
        if (db.z / PART_SZ == p) csr[atomicAdd(&cursor[db.z], 1)] = sb.z;
        if (db.w / PART_SZ == p) csr[atomicAdd(&cursor[db.w], 1)] = sb.w;
    }
}

// ---------------- hierarchical scan ----------------

__global__ __launch_bounds__(SCAN_BLOCK) void scan_partial_kernel(const int* __restrict__ deg,
                                                                  int* __restrict__ partials) {
    __shared__ int red[SCAN_BLOCK / 64];
    int i = blockIdx.x * SCAN_BLOCK + threadIdx.x;
    int v = (i < N_NODES) ? deg[i] : 0;
    for (int o = 32; o > 0; o >>= 1) v += __shfl_down(v, o, 64);
    if ((threadIdx.x & 63) == 0) red[threadIdx.x >> 6] = v;
    __syncthreads();
    if (threadIdx.x == 0) {
        int s = 0;
#pragma unroll
        for (int w = 0; w < SCAN_BLOCK / 64; ++w) s += red[w];
        partials[blockIdx.x] = s;
    }
}

__global__ __launch_bounds__(512) void scan_partials_kernel(int* __restrict__ partials,
                                                            int* __restrict__ off) {
    __shared__ int sm[512];
    int t = threadIdx.x;
    int v = (t < SCAN_NB) ? partials[t] : 0;
    sm[t] = v;
    __syncthreads();
    for (int o = 1; o < 512; o <<= 1) {
        int u = (t >= o) ? sm[t - o] : 0;
        __syncthreads();
        sm[t] += u;
        __syncthreads();
    }
    if (t < SCAN_NB) partials[t] = sm[t] - v;
    if (t == 0) off[N_NODES] = sm[511];
}

__global__ __launch_bounds__(SCAN_BLOCK) void scan_scatter_kernel(const int* __restrict__ deg,
                                                                  const int* __restrict__ partials,
                                                                  int* __restrict__ off,
                                                                  int* __restrict__ cursor) {
    __shared__ int sm[SCAN_BLOCK];
    int t = threadIdx.x;
    int i = blockIdx.x * SCAN_BLOCK + t;
    int v = (i < N_NODES) ? deg[i] : 0;
    sm[t] = v;
    __syncthreads();
    for (int o = 1; o < SCAN_BLOCK; o <<= 1) {
        int u = (t >= o) ? sm[t - o] : 0;
        __syncthreads();
        sm[t] += u;
        __syncthreads();
    }
    if (i < N_NODES) {
        int r = partials[blockIdx.x] + sm[t] - v;
        off[i] = r;
        cursor[i] = r;
    }
}

// ---------------- W -> bf16 B-fragment layout (verified R5) ----------------

__global__ __launch_bounds__(64) void wprep_kernel(const float* __restrict__ W1,
                                                   const float* __restrict__ W2,
                                                   const float* __restrict__ W3,
                                                   uint4* __restrict__ wb4) {
    int b = blockIdx.x;           // l*32 + nt*4 + kk
    int l = b >> 5;
    int nt = (b >> 2) & 7;
    int kk = b & 3;
    int lane = threadIdx.x;
    const float* W = (l == 0) ? W1 : (l == 1) ? W2 : W3;
    int row = nt * 16 + (lane & 15);
    int cb = kk * 32 + (lane >> 4) * 8;
    const float* g = W + row * DIM + cb;
    float4 f0 = *(const float4*)g;
    float4 f1 = *(const float4*)(g + 4);
    uint4 o;
    o.x = pk2(f0.x, f0.y);
    o.y = pk2(f0.z, f0.w);
    o.z = pk2(f1.x, f1.y);
    o.w = pk2(f1.z, f1.w);
    wb4[(size_t)b * 64 + lane] = o;
}

// ---------------- x f32 -> bf16 (padded rows zeroed) ----------------

__global__ __launch_bounds__(256) void xconv_kernel(const float* __restrict__ x,
                                                    unsigned short* __restrict__ xb) {
    int i = blockIdx.x * blockDim.x + threadIdx.x;
    int stride = gridDim.x * blockDim.x;
    const int TOT = N_PAD * DIM / 8;
    for (; i < TOT; i += stride) {
        int row = i >> 4;
        int ks = i & 15;
        uint4 o = {0, 0, 0, 0};
        if (row < N_NODES) {
            const float* g = x + (size_t)row * DIM + ks * 8;
            float4 f0 = *(const float4*)g;
            float4 f1 = *(const float4*)(g + 4);
            o.x = pk2(f0.x, f0.y);
            o.y = pk2(f0.z, f0.w);
            o.z = pk2(f1.x, f1.y);
            o.w = pk2(f1.z, f1.w);
        }
        ((uint4*)xb)[i] = o;
    }
}

// ---------------- fused agg + MFMA GEMM ----------------
// WAVE-PER-ROW gather (R8 lesson: 4 rows/wave diverged ~28% on k-loop trips).
// lane = esl*16 + dl: 4 edge-slots x 16 dim-lanes; one wave-load still
// gathers 4x256B = 1KB. Per-row partials combined by shfl_xor(16/32).
// BN+ReLU of previous layer inline. MFMA phase verified R5.

template <bool BN>
__global__ __launch_bounds__(256) void agg_gemm_kernel(const unsigned short* __restrict__ hin,
                                                       const int* __restrict__ off,
                                                       const int* __restrict__ csr,
                                                       const float* __restrict__ eps_arr, int layer,
                                                       const float* __restrict__ csum_prev,
                                                       const float* __restrict__ csq_prev,
                                                       const float* __restrict__ gamma_prev,
                                                       const float* __restrict__ beta_prev,
                                                       const uint4* __restrict__ wb4,
                                                       unsigned short* __restrict__ y,
                                                       float* __restrict__ csum_out,
                                                       float* __restrict__ csq_out) {
    __shared__ unsigned short tile[64 * DIM];  // bf16, 16B-granular XOR swizzle
    __shared__ float sstat[4][DIM];
    __shared__ float sstatq[4][DIM];
    int tid = threadIdx.x;
    int row0 = blockIdx.x * 64;
    int wv = tid >> 6;          // wave 0..3, owns rows wv*16 .. wv*16+15
    int esl = (tid >> 4) & 3;   // edge slot within wave
    int dl = tid & 15;          // dim lane: dims dl*8 .. dl*8+7
    float se = 1.0f + eps_arr[layer];
    float sc[8], sh[8];
    if (BN) {
#pragma unroll
        for (int j = 0; j < 8; ++j) {
            int d = dl * 8 + j;
            float m = csum_prev[d] * (1.0f / N_NODES);
            float var = csq_prev[d] * (1.0f / N_NODES) - m * m;
            float s = gamma_prev[d] * rsqrtf(var + 1e-5f);
            sc[j] = s;
            sh[j] = beta_prev[d] - m * s;
        }
    }
    const uint4* base = (const uint4*)hin + dl;
    const size_t RS = DIM / 8;  // uint4 per row

#pragma unroll 1
    for (int r = 0; r < 16; ++r) {
        int trow = wv * 16 + r;
        int row = row0 + trow;
        float a[8] = {0.f, 0.f, 0.f, 0.f, 0.f, 0.f, 0.f, 0.f};
        float s8[8] = {0.f, 0.f, 0.f, 0.f, 0.f, 0.f, 0.f, 0.f};
        if (row < N_NODES) {
            {   // self term (all lanes; 4-slot broadcast of 256B row)
                uint4 pv = base[(size_t)row * RS];
                float v[8];
                dec2(pv.x, v[0], v[1]); dec2(pv.y, v[2], v[3]);
                dec2(pv.z, v[4], v[5]); dec2(pv.w, v[6], v[7]);
#pragma unroll
                for (int j = 0; j < 8; ++j)
                    s8[j] = BN ? fmaxf(fmaf(v[j], sc[j], sh[j]), 0.f) : v[j];
            }
            int k = off[row], e = off[row + 1];
            // main: 8 edges per trip, 2 gathers in flight per lane
            for (; k + 8 <= e; k += 8) {
                int i0 = csr[k + esl];
                int i1 = csr[k + 4 + esl];
                uint4 p0 = base[(size_t)i0 * RS];
                uint4 p1 = base[(size_t)i1 * RS];
                acc8<BN>(p0, a, sc, sh);
                acc8<BN>(p1, a, sc, sh);
            }
            // tail: predicated quads
            for (; k < e; k += 4) {
                int kk = k + esl;
                if (kk < e) {
                    uint4 p0 = base[(size_t)csr[kk] * RS];
                    acc8<BN>(p0, a, sc, sh);
                }
            }
        }
        // combine the 4 edge-slots (butterfly over lane bits 4,5)
#pragma unroll
        for (int j = 0; j < 8; ++j) {
            a[j] += __shfl_xor(a[j], 16);
            a[j] += __shfl_xor(a[j], 32);
            a[j] = fmaf(se, s8[j], a[j]);
        }
        if (esl == 0) {
            uint4 pw;
            pw.x = pk2(a[0], a[1]);
            pw.y = pk2(a[2], a[3]);
            pw.z = pk2(a[4], a[5]);
            pw.w = pk2(a[6], a[7]);
            int byte = (trow * 256 + dl * 16) ^ ((trow & 7) << 4);
            *(uint4*)((char*)tile + byte) = pw;
        }
    }
    __syncthreads();

    // ---- MFMA phase (layout verified R5) ----
    int w = tid >> 6;
    int l = tid & 63;
    int lr = l & 15;
    int lg = l >> 4;
    bf16x8 a[4];
#pragma unroll
    for (int kk = 0; kk < 4; ++kk) {
        int row = w * 16 + lr;
        int byte = (row * 256 + kk * 64 + lg * 16) ^ ((row & 7) << 4);
        a[kk] = __builtin_bit_cast(bf16x8, *(uint4*)((char*)tile + byte));
    }

#pragma unroll
    for (int nt = 0; nt < 8; ++nt) {
        f32x4 acc = {0.0f, 0.0f, 0.0f, 0.0f};
#pragma unroll
        for (int kk = 0; kk < 4; ++kk) {
            bf16x8 b = __builtin_bit_cast(bf16x8, wb4[(nt * 4 + kk) * 64 + l]);
            acc = __builtin_amdgcn_mfma_f32_16x16x32_bf16(a[kk], b, acc, 0, 0, 0);
        }
        int col = nt * 16 + lr;
        size_t base2 = (size_t)(row0 + w * 16 + lg * 4) * DIM + col;
        y[base2] = f2bf(acc[0]);
        y[base2 + DIM] = f2bf(acc[1]);
        y[base2 + 2 * DIM] = f2bf(acc[2]);
        y[base2 + 3 * DIM] = f2bf(acc[3]);
        float s = acc[0] + acc[1] + acc[2] + acc[3];
        float q = acc[0] * acc[0] + acc[1] * acc[1] + acc[2] * acc[2] + acc[3] * acc[3];
        s += __shfl_xor(s, 16);
        s += __shfl_xor(s, 32);
        q += __shfl_xor(q, 16);
        q += __shfl_xor(q, 32);
        if (lg == 0) {
            sstat[w][col] = s;
            sstatq[w][col] = q;
        }
    }
    __syncthreads();
    if (tid < DIM) {
        float s = sstat[0][tid] + sstat[1][tid] + sstat[2][tid] + sstat[3][tid];
        float q = sstatq[0][tid] + sstatq[1][tid] + sstatq[2][tid] + sstatq[3][tid];
        atomicAdd(&csum_out[tid], s);
        atomicAdd(&csq_out[tid], q);
    }
}

// ---------------- global mean pool (final BN+ReLU inline, 4-node MLP) -------

__global__ __launch_bounds__(128) void pool_kernel(const unsigned short* __restrict__ y,
                                                   const int* __restrict__ batch,
                                                   const float* __restrict__ csum,
                                                   const float* __restrict__ csq,
                                                   const float* __restrict__ gamma,
                                                   const float* __restrict__ beta,
                                                   float* __restrict__ out) {
    int gph = blockIdx.x;
    int d = threadIdx.x;
    float m = csum[d] * (1.0f / N_NODES);
    float var = csq[d] * (1.0f / N_NODES) - m * m;
    float sc = gamma[d] * rsqrtf(var + 1e-5f);
    float sh = beta[d] - m * sc;
    int lo = 0, hi = N_NODES;
    while (lo < hi) {
        int mid = (lo + hi) >> 1;
        if (batch[mid] < gph) lo = mid + 1; else hi = mid;
    }
    int start = lo;
    hi = N_NODES;
    while (lo < hi) {
        int mid = (lo + hi) >> 1;
        if (batch[mid] < gph + 1) lo = mid + 1; else hi = mid;
    }
    int end = lo;
    float s0 = 0.f, s1 = 0.f, s2 = 0.f, s3 = 0.f;
    int n = start;
    for (; n + 3 < end; n += 4) {
        float v0 = bf2f(y[(size_t)n * DIM + d]);
        float v1 = bf2f(y[(size_t)(n + 1) * DIM + d]);
        float v2 = bf2f(y[(size_t)(n + 2) * DIM + d]);
        float v3 = bf2f(y[(size_t)(n + 3) * DIM + d]);
        s0 += fmaxf(fmaf(v0, sc, sh), 0.0f);
        s1 += fmaxf(fmaf(v1, sc, sh), 0.0f);
        s2 += fmaxf(fmaf(v2, sc, sh), 0.0f);
        s3 += fmaxf(fmaf(v3, sc, sh), 0.0f);
    }
    for (; n < end; ++n) {
        float v = bf2f(y[(size_t)n * DIM + d]);
        s0 += fmaxf(fmaf(v, sc, sh), 0.0f);
    }
    float s = (s0 + s1) + (s2 + s3);
    out[gph * DIM + d] = s / fmaxf((float)(end - start), 1.0f);
}

// ---------------- launch ----------------

extern "C" void kernel_launch(void* const* d_in, const int* in_sizes, int n_in,
                              void* d_out, int out_size, void* d_ws, size_t ws_size,
                              hipStream_t stream) {
    const float* x = (const float*)d_in[0];
    const int* ei = (const int*)d_in[1];
    const int* batch = (const int*)d_in[2];
    const float* Wp[3] = {(const float*)d_in[3], (const float*)d_in[5], (const float*)d_in[7]};
    const float* eps = (const float*)d_in[9];
    const float* gamma = (const float*)d_in[10];
    const float* beta = (const float*)d_in[11];
    float* out = (float*)d_out;

    char* ws = (char*)d_ws;
    size_t o = 0;
    auto alloc = [&](size_t bytes) {
        void* p = ws + o;
        o = (o + bytes + 255) & ~(size_t)255;
        return p;
    };
    int* deg = (int*)alloc(N_NODES * sizeof(int));
    int* off = (int*)alloc((N_NODES + 1) * sizeof(int));
    int* cursor = (int*)alloc(N_NODES * sizeof(int));
    int* partials = (int*)alloc(SCAN_NB * sizeof(int));
    int* csr = (int*)alloc(N_EDGES * sizeof(int));
    uint4* wb4 = (uint4*)alloc(3 * 8 * 4 * 64 * 16);
    float* csums = (float*)alloc(3 * DIM * sizeof(float));
    float* csqs = (float*)alloc(3 * DIM * sizeof(float));
    unsigned short* xb = (unsigned short*)alloc((size_t)N_PAD * DIM * 2);
    unsigned short* y0 = (unsigned short*)alloc((size_t)N_PAD * DIM * 2);
    unsigned short* y1 = (unsigned short*)alloc((size_t)N_PAD * DIM * 2);

    hipMemsetAsync(deg, 0, N_NODES * sizeof(int), stream);
    hipMemsetAsync(csums, 0, 3 * DIM * sizeof(float), stream);
    hipMemsetAsync(csqs, 0, 3 * DIM * sizeof(float), stream);

    hist_kernel<<<1024, 256, 0, stream>>>(ei + N_EDGES, deg);
    scan_partial_kernel<<<SCAN_NB, SCAN_BLOCK, 0, stream>>>(deg, partials);
    scan_partials_kernel<<<1, 512, 0, stream>>>(partials, off);
    scan_scatter_kernel<<<SCAN_NB, SCAN_BLOCK, 0, stream>>>(deg, partials, off, cursor);
    fill_part_kernel<<<2048, 256, 0, stream>>>(ei, ei + N_EDGES, cursor, csr);
    wprep_kernel<<<96, 64, 0, stream>>>(Wp[0], Wp[1], Wp[2], wb4);
    xconv_kernel<<<2048, 256, 0, stream>>>(x, xb);

    const int NBLK = N_PAD / 64;  // 1563
    agg_gemm_kernel<false><<<NBLK, 256, 0, stream>>>(xb, off, csr, eps, 0,
                                                     nullptr, nullptr, nullptr, nullptr,
                                                     wb4, y0, csums, csqs);
    agg_gemm_kernel<true><<<NBLK, 256, 0, stream>>>(y0, off, csr, eps, 1,
                                                    csums, csqs, gamma, beta,
                                                    wb4 + 2048, y1, csums + DIM, csqs + DIM);
    agg_gemm_kernel<true><<<NBLK, 256, 0, stream>>>(y1, off, csr, eps, 2,
                                                    csums + DIM, csqs + DIM, gamma + DIM, beta + DIM,
                                                    wb4 + 4096, y0, csums + 2 * DIM, csqs + 2 * DIM);
    pool_kernel<<<N_GRAPHS, DIM, 0, stream>>>(y0, batch, csums + 2 * DIM, csqs + 2 * DIM,
                                              gamma + 2 * DIM, beta + 2 * DIM, out);
}